// Round 14
// baseline (201.067 us; speedup 1.0000x reference)
//
#include <hip/hip_runtime.h>
#include <hip/hip_bf16.h>

#define S_TOT 2720

// ---------------- fp32 -> bf16 weight conversion (run once per launch, into d_ws)
__global__ void cvt_bf16_kernel(const float* __restrict__ src, __hip_bfloat16* __restrict__ dst,
                                int n) {
    int i = blockIdx.x * 256 + threadIdx.x;
    if (i < n) dst[i] = __float2bfloat16(src[i]);
}

// ---------------- down projection: t0[b,pos,c] = x[b,pos,:] @ w_down + b_down
__global__ void down_kernel(const float* __restrict__ x, const float* __restrict__ w,
                            const float* __restrict__ b, float* __restrict__ t0) {
    int id = blockIdx.x * 256 + threadIdx.x;     // B*2048*32 = 131072
    int c = id & 31;
    int r = id >> 5;
    const float* xr = x + (size_t)r * 128;
    float a0 = b[c], a1 = 0.f, a2 = 0.f, a3 = 0.f;
#pragma unroll
    for (int k = 0; k < 128; k += 4) {
        a0 += xr[k]     * w[(k)     * 32 + c];
        a1 += xr[k + 1] * w[(k + 1) * 32 + c];
        a2 += xr[k + 2] * w[(k + 2) * 32 + c];
        a3 += xr[k + 3] * w[(k + 3) * 32 + c];
    }
    t0[id] = (a0 + a1) + (a2 + a3);
}

// ---------------- conv (stride4,k4) + bias + BN + ELU
__global__ void conv_kernel(const float* __restrict__ in, float* __restrict__ pooled,
                            const float* __restrict__ cw, const float* __restrict__ cb,
                            const float* __restrict__ bg, const float* __restrict__ bb,
                            const float* __restrict__ bm, const float* __restrict__ bv,
                            int level, int in_bstride, int in_off, int Lout, int out_off,
                            int total) {
    int id = blockIdx.x * 256 + threadIdx.x;
    if (id >= total) return;
    int co = id & 31;
    int lo = (id >> 5) % Lout;
    int b  = id / (32 * Lout);
    const float* ib = in + (size_t)(b * in_bstride + in_off + lo * 4) * 32;
    const float* w  = cw + (size_t)(level * 32 + co) * 32 * 4;
    float acc0 = 0.f, acc1 = 0.f, acc2 = 0.f, acc3 = 0.f;
#pragma unroll
    for (int ci = 0; ci < 32; ++ci) {
        acc0 += ib[0 * 32 + ci] * w[ci * 4 + 0];
        acc1 += ib[1 * 32 + ci] * w[ci * 4 + 1];
        acc2 += ib[2 * 32 + ci] * w[ci * 4 + 2];
        acc3 += ib[3 * 32 + ci] * w[ci * 4 + 3];
    }
    float acc = ((acc0 + acc1) + (acc2 + acc3)) + cb[level * 32 + co];
    acc = (acc - bm[level * 32 + co]) * rsqrtf(bv[level * 32 + co] + 1e-5f)
          * bg[level * 32 + co] + bb[level * 32 + co];
    acc = acc > 0.f ? acc : expm1f(acc);
    pooled[(size_t)(b * 672 + out_off + lo) * 32 + co] = acc;
}

// ---------------- build h rows (copy x | pooled@w_up+b_up) fused with LN0. wave per row.
__global__ void build_ln_kernel(const float* __restrict__ x, const float* __restrict__ pooled,
                                const float* __restrict__ w_up, const float* __restrict__ b_up,
                                const float* __restrict__ g, const float* __restrict__ bta,
                                float* __restrict__ h) {
    int wave = threadIdx.x >> 6;
    int lane = threadIdx.x & 63;
    int row = blockIdx.x * 4 + wave;          // 5440 rows
    int b = row / S_TOT, s = row % S_TOT;
    float v0, v1;
    if (s < 2048) {
        const float* xr = x + (size_t)(b * 2048 + s) * 128;
        v0 = xr[lane]; v1 = xr[lane + 64];
    } else {
        int p = s - 2048;
        const float* pr = pooled + (size_t)(b * 672 + p) * 32;
        float a0 = b_up[lane], a1 = b_up[lane + 64];
        float a2 = 0.f, a3 = 0.f;
#pragma unroll
        for (int k = 0; k < 32; k += 2) {
            float p0 = pr[k], p1 = pr[k + 1];
            a0 += p0 * w_up[k * 128 + lane];
            a1 += p0 * w_up[k * 128 + lane + 64];
            a2 += p1 * w_up[(k + 1) * 128 + lane];
            a3 += p1 * w_up[(k + 1) * 128 + lane + 64];
        }
        v0 = a0 + a2; v1 = a1 + a3;
    }
    float sum = v0 + v1;
#pragma unroll
    for (int off = 32; off; off >>= 1) sum += __shfl_xor(sum, off);
    float mu = sum * (1.f / 128.f);
    float d0 = v0 - mu, d1 = v1 - mu;
    float vs = d0 * d0 + d1 * d1;
#pragma unroll
    for (int off = 32; off; off >>= 1) vs += __shfl_xor(vs, off);
    float inv = rsqrtf(vs * (1.f / 128.f) + 1e-5f);
    h[(size_t)row * 128 + lane]      = d0 * inv * g[lane]      + bta[lane];
    h[(size_t)row * 128 + lane + 64] = d1 * inv * g[lane + 64] + bta[lane + 64];
}

// ---------------- QKV: grid = 340 row-tiles x 3 mats = 1020 blocks. 16 rows/block.
// Wave owns 4 rows; lane owns 2 cols; float2 weight loads + depth-1 prefetch.
__global__ __launch_bounds__(256) void qkv_kernel(const float* __restrict__ H,
                                                  const float* __restrict__ wq,
                                                  const float* __restrict__ wk,
                                                  const float* __restrict__ wv,
                                                  float* __restrict__ q, float* __restrict__ k,
                                                  float* __restrict__ v) {
    __shared__ float hs[16][128];             // 8 KB
    int tid = threadIdx.x;
    int mat = blockIdx.x % 3;
    int r0  = (blockIdx.x / 3) * 16;          // 340 row-tiles
    const float* W = (mat == 0) ? wq : (mat == 1) ? wk : wv;
    float* O       = (mat == 0) ? q  : (mat == 1) ? k  : v;
    {
        const float4* src = (const float4*)(H + (size_t)r0 * 128);
        float4* dst = (float4*)hs;
        dst[tid] = src[tid];
        dst[tid + 256] = src[tid + 256];
    }
    __syncthreads();
    int rbase = (tid >> 6) * 4, j0 = (tid & 63) * 2;
    float acc[4][2];
#pragma unroll
    for (int r = 0; r < 4; ++r) { acc[r][0] = 0.f; acc[r][1] = 0.f; }
    float2 wf[4], wfn[4];
#pragma unroll
    for (int kk = 0; kk < 4; ++kk) wf[kk] = *(const float2*)&W[kk * 128 + j0];
    for (int kt = 0; kt < 128; kt += 4) {
        int ktn = (kt + 4) & 127;
#pragma unroll
        for (int kk = 0; kk < 4; ++kk) wfn[kk] = *(const float2*)&W[(ktn + kk) * 128 + j0];
#pragma unroll
        for (int r = 0; r < 4; ++r) {
            float4 ha = *(const float4*)&hs[rbase + r][kt];
            acc[r][0] += ha.x * wf[0].x; acc[r][1] += ha.x * wf[0].y;
            acc[r][0] += ha.y * wf[1].x; acc[r][1] += ha.y * wf[1].y;
            acc[r][0] += ha.z * wf[2].x; acc[r][1] += ha.z * wf[2].y;
            acc[r][0] += ha.w * wf[3].x; acc[r][1] += ha.w * wf[3].y;
        }
#pragma unroll
        for (int kk = 0; kk < 4; ++kk) wf[kk] = wfn[kk];
    }
#pragma unroll
    for (int r = 0; r < 4; ++r)
        *(float2*)&O[(size_t)(r0 + rbase + r) * 128 + j0] = make_float2(acc[r][0], acc[r][1]);
}

// ---------------- sparse pyramid attention, 4 lanes per query (each owns 8 dims)
__global__ void attn_kernel(const float* __restrict__ Q, const float* __restrict__ K,
                            const float* __restrict__ V, float* __restrict__ O) {
    int id = blockIdx.x * 256 + threadIdx.x;     // 87040
    int d0 = (id & 3) * 8;
    int gid = id >> 2;                           // 21760 queries
    int i  = gid % S_TOT;
    int hh = (gid / S_TOT) & 3;
    int b  = gid / (S_TOT * 4);
    int li, s;
    if (i < 2048)      { li = 0; s = 0;    }
    else if (i < 2560) { li = 1; s = 2048; }
    else if (i < 2688) { li = 2; s = 2560; }
    else               { li = 3; s = 2688; }
    int sz = (li == 0) ? 2048 : (li == 1) ? 512 : (li == 2) ? 128 : 32;
    int pstart = (li == 0) ? 2048 : (li == 1) ? 2560 : 2688;
    int cstart = (li == 1) ? 0 : (li == 2) ? 2048 : 2560;

    const float* qp = Q + ((size_t)(b * S_TOT + i) * 128) + hh * 32 + d0;
    float4 qa = *(const float4*)qp;
    float4 qb = *(const float4*)(qp + 4);
    const float invt = 0.17677669529663687f;     // 1/sqrt(32)

    float sc[10];
    int   nj[10];
    bool  vl[10];
#pragma unroll
    for (int slot = 0; slot < 10; ++slot) {
        int j; bool valid;
        if (slot < 5)       { j = i - 2 + slot;                         valid = (j >= s) && (j < s + sz); }
        else if (slot == 5) { j = pstart + ((i - s) >> 2);              valid = (li < 3); }
        else                { j = cstart + ((i - s) << 2) + (slot - 6); valid = (li > 0); }
        nj[slot] = j; vl[slot] = valid;
        float dot = 0.f;
        if (valid) {
            const float* kp = K + ((size_t)(b * S_TOT + j) * 128) + hh * 32 + d0;
            float4 ka = *(const float4*)kp;
            float4 kb = *(const float4*)(kp + 4);
            dot = qa.x * ka.x + qa.y * ka.y + qa.z * ka.z + qa.w * ka.w
                + qb.x * kb.x + qb.y * kb.y + qb.z * kb.z + qb.w * kb.w;
        }
        dot += __shfl_xor(dot, 1);
        dot += __shfl_xor(dot, 2);
        sc[slot] = valid ? dot * invt : -1e30f;
    }
    float mx = sc[0];
#pragma unroll
    for (int slot = 1; slot < 10; ++slot) mx = fmaxf(mx, sc[slot]);
    float ssum = 0.f;
#pragma unroll
    for (int slot = 0; slot < 10; ++slot) { sc[slot] = __expf(sc[slot] - mx); ssum += sc[slot]; }
    float rinv = 1.f / ssum;
    float4 oa = {0.f, 0.f, 0.f, 0.f}, ob = {0.f, 0.f, 0.f, 0.f};
#pragma unroll
    for (int slot = 0; slot < 10; ++slot) {
        if (vl[slot]) {
            float p = sc[slot] * rinv;
            const float* vp = V + ((size_t)(b * S_TOT + nj[slot]) * 128) + hh * 32 + d0;
            float4 va = *(const float4*)vp;
            float4 vb = *(const float4*)(vp + 4);
            oa.x += p * va.x; oa.y += p * va.y; oa.z += p * va.z; oa.w += p * va.w;
            ob.x += p * vb.x; ob.y += p * vb.y; ob.z += p * vb.z; ob.w += p * vb.w;
        }
    }
    float* op = O + ((size_t)(b * S_TOT + i) * 128) + hh * 32 + d0;
    *(float4*)op = oa;
    *(float4*)(op + 4) = ob;
}

// ---------------- o-proj + residual + LN1. 680 blocks x 8 rows; wave owns 2 rows.
__global__ __launch_bounds__(256) void o_ln_kernel(const float* __restrict__ Ob,
                                                   const float* __restrict__ wo,
                                                   const float* __restrict__ g,
                                                   const float* __restrict__ bta,
                                                   float* __restrict__ h) {
    __shared__ float os[8][128];              // 4 KB
    int tid = threadIdx.x;
    int r0 = blockIdx.x * 8;                  // 680 blocks
    ((float4*)os)[tid] = ((const float4*)(Ob + (size_t)r0 * 128))[tid];
    __syncthreads();
    int rbase = (tid >> 6) * 2, j0 = (tid & 63) * 2;
    float acc[2][2];
    acc[0][0] = acc[0][1] = acc[1][0] = acc[1][1] = 0.f;
    float2 wf[4], wfn[4];
#pragma unroll
    for (int kk = 0; kk < 4; ++kk) wf[kk] = *(const float2*)&wo[kk * 128 + j0];
    for (int kt = 0; kt < 128; kt += 4) {
        int ktn = (kt + 4) & 127;
#pragma unroll
        for (int kk = 0; kk < 4; ++kk) wfn[kk] = *(const float2*)&wo[(ktn + kk) * 128 + j0];
#pragma unroll
        for (int r = 0; r < 2; ++r) {
            float4 ha = *(const float4*)&os[rbase + r][kt];
            acc[r][0] += ha.x * wf[0].x; acc[r][1] += ha.x * wf[0].y;
            acc[r][0] += ha.y * wf[1].x; acc[r][1] += ha.y * wf[1].y;
            acc[r][0] += ha.z * wf[2].x; acc[r][1] += ha.z * wf[2].y;
            acc[r][0] += ha.w * wf[3].x; acc[r][1] += ha.w * wf[3].y;
        }
#pragma unroll
        for (int kk = 0; kk < 4; ++kk) wf[kk] = wfn[kk];
    }
    float g0 = g[j0], g1 = g[j0 + 1], bt0 = bta[j0], bt1 = bta[j0 + 1];
#pragma unroll
    for (int r = 0; r < 2; ++r) {
        size_t row = (size_t)(r0 + rbase + r) * 128;
        float2 res = *(const float2*)&h[row + j0];
        float v0 = acc[r][0] + res.x, v1 = acc[r][1] + res.y;
        float sum = v0 + v1;
#pragma unroll
        for (int off = 32; off; off >>= 1) sum += __shfl_xor(sum, off);
        float mu = sum * (1.f / 128.f);
        float e0 = v0 - mu, e1 = v1 - mu;
        float vs = e0 * e0 + e1 * e1;
#pragma unroll
        for (int off = 32; off; off >>= 1) vs += __shfl_xor(vs, off);
        float inv = rsqrtf(vs * (1.f / 128.f) + 1e-6f);
        *(float2*)&h[row + j0] = make_float2(e0 * inv * g0 + bt0, e1 * inv * g1 + bt1);
    }
}

// ---------------- fused FFN + residual + LN2. 1360 blocks x 4 rows, 256 thr, bf16 weights,
// depth-1 prefetch. LDS 18 KB -> high occupancy ceiling.
__global__ __launch_bounds__(256) void ffn_kernel(const float* __restrict__ H,
                                                  const unsigned int* __restrict__ w1u,
                                                  const float* __restrict__ b1,
                                                  const unsigned int* __restrict__ w2u,
                                                  const float* __restrict__ b2,
                                                  const float* __restrict__ g,
                                                  const float* __restrict__ bta,
                                                  float* __restrict__ h) {
    __shared__ float hs[4][128];              // 2 KB
    __shared__ float f1s[4][512];             // 8 KB
    __shared__ float part[4][4][128];         // 8 KB
    int tid = threadIdx.x;
    int r0 = blockIdx.x * 4;                  // 1360 blocks
    if (tid < 128) ((float4*)hs)[tid] = ((const float4*)(H + (size_t)r0 * 128))[tid];
    __syncthreads();
    // stage 1: thread owns cols (2*tid, 2*tid+1) of 512; packed-bf16 weight uint per k
    {
        float acc[4][2];
#pragma unroll
        for (int r = 0; r < 4; ++r) { acc[r][0] = 0.f; acc[r][1] = 0.f; }
        unsigned int wf[4], wfn[4];
#pragma unroll
        for (int kk = 0; kk < 4; ++kk) wf[kk] = w1u[kk * 256 + tid];
        for (int kt = 0; kt < 128; kt += 4) {
            int ktn = (kt + 4) & 127;
#pragma unroll
            for (int kk = 0; kk < 4; ++kk) wfn[kk] = w1u[(ktn + kk) * 256 + tid];
            float wlo[4], whi[4];
#pragma unroll
            for (int kk = 0; kk < 4; ++kk) {
                wlo[kk] = __uint_as_float(wf[kk] << 16);
                whi[kk] = __uint_as_float(wf[kk] & 0xffff0000u);
            }
#pragma unroll
            for (int r = 0; r < 4; ++r) {
                float4 ha = *(const float4*)&hs[r][kt];
                acc[r][0] += ha.x * wlo[0]; acc[r][1] += ha.x * whi[0];
                acc[r][0] += ha.y * wlo[1]; acc[r][1] += ha.y * whi[1];
                acc[r][0] += ha.z * wlo[2]; acc[r][1] += ha.z * whi[2];
                acc[r][0] += ha.w * wlo[3]; acc[r][1] += ha.w * whi[3];
            }
#pragma unroll
            for (int kk = 0; kk < 4; ++kk) wf[kk] = wfn[kk];
        }
        int j0 = tid * 2;
        float2 bv = *(const float2*)&b1[j0];
#pragma unroll
        for (int r = 0; r < 4; ++r)
            *(float2*)&f1s[r][j0] = make_float2(fmaxf(acc[r][0] + bv.x, 0.f),
                                                fmaxf(acc[r][1] + bv.y, 0.f));
    }
    __syncthreads();
    // stage 2: seg = tid>>6 (4 segs x 128 j's); thread owns d0 = (tid&63)*2; 4 rows
    {
        int seg = tid >> 6, t6 = tid & 63, jb = seg * 128;
        float acc[4][2];
#pragma unroll
        for (int r = 0; r < 4; ++r) { acc[r][0] = 0.f; acc[r][1] = 0.f; }
        unsigned int wf[4], wfn[4];
#pragma unroll
        for (int jj = 0; jj < 4; ++jj) wf[jj] = w2u[(jb + jj) * 64 + t6];
        for (int jt = 0; jt < 128; jt += 4) {
            int jtn = (jt + 4) & 127;
#pragma unroll
            for (int jj = 0; jj < 4; ++jj) wfn[jj] = w2u[(jb + jtn + jj) * 64 + t6];
            float wlo[4], whi[4];
#pragma unroll
            for (int jj = 0; jj < 4; ++jj) {
                wlo[jj] = __uint_as_float(wf[jj] << 16);
                whi[jj] = __uint_as_float(wf[jj] & 0xffff0000u);
            }
#pragma unroll
            for (int r = 0; r < 4; ++r) {
                float4 fa = *(const float4*)&f1s[r][jb + jt];
                acc[r][0] += fa.x * wlo[0]; acc[r][1] += fa.x * whi[0];
                acc[r][0] += fa.y * wlo[1]; acc[r][1] += fa.y * whi[1];
                acc[r][0] += fa.z * wlo[2]; acc[r][1] += fa.z * whi[2];
                acc[r][0] += fa.w * wlo[3]; acc[r][1] += fa.w * whi[3];
            }
#pragma unroll
            for (int jj = 0; jj < 4; ++jj) wf[jj] = wfn[jj];
        }
        int d0 = t6 * 2;
#pragma unroll
        for (int r = 0; r < 4; ++r)
            *(float2*)&part[seg][r][d0] = make_float2(acc[r][0], acc[r][1]);
    }
    __syncthreads();
    // final: wave per row (4 waves, 4 rows), 2 elems/lane; 64-lane shuffle LN (verified pattern)
    {
        int r = tid >> 6, lane = tid & 63;
        size_t row = (size_t)(r0 + r) * 128;
        float v0 = part[0][r][lane]      + part[1][r][lane]      + part[2][r][lane]
                 + part[3][r][lane]      + b2[lane]      + h[row + lane];
        float v1 = part[0][r][lane + 64] + part[1][r][lane + 64] + part[2][r][lane + 64]
                 + part[3][r][lane + 64] + b2[lane + 64] + h[row + lane + 64];
        float sum = v0 + v1;
#pragma unroll
        for (int off = 32; off; off >>= 1) sum += __shfl_xor(sum, off);
        float mu = sum * (1.f / 128.f);
        float e0 = v0 - mu, e1 = v1 - mu;
        float vs = e0 * e0 + e1 * e1;
#pragma unroll
        for (int off = 32; off; off >>= 1) vs += __shfl_xor(vs, off);
        float inv = rsqrtf(vs * (1.f / 128.f) + 1e-6f);
        h[row + lane]      = e0 * inv * g[lane]      + bta[lane];
        h[row + lane + 64] = e1 * inv * g[lane + 64] + bta[lane + 64];
    }
}

// ---------------- gather refer-points, float4
__global__ void gather_kernel(const float* __restrict__ H, const int* __restrict__ idx,
                              float* __restrict__ out) {
    int id = blockIdx.x * 256 + threadIdx.x;     // 524288 float4s
    int d4 = id & 31;
    int j = (id >> 5) & 3;
    int t = (id >> 7) & 2047;
    int b = id >> 18;
    int src = idx[t * 4 + j];
    ((float4*)out)[id] = *(const float4*)&H[((size_t)(b * S_TOT + src) * 128) + d4 * 4];
}

extern "C" void kernel_launch(void* const* d_in, const int* in_sizes, int n_in,
                              void* d_out, int out_size, void* d_ws, size_t ws_size,
                              hipStream_t stream) {
    (void)in_sizes; (void)n_in; (void)out_size; (void)ws_size;
    const float* x       = (const float*)d_in[0];
    const float* w_down  = (const float*)d_in[1];
    const float* b_down  = (const float*)d_in[2];
    const float* conv_w  = (const float*)d_in[3];
    const float* conv_b  = (const float*)d_in[4];
    const float* bn_g    = (const float*)d_in[5];
    const float* bn_b    = (const float*)d_in[6];
    const float* bn_m    = (const float*)d_in[7];
    const float* bn_v    = (const float*)d_in[8];
    const float* w_up    = (const float*)d_in[9];
    const float* b_up    = (const float*)d_in[10];
    const float* ln0_g   = (const float*)d_in[11];
    const float* ln0_b   = (const float*)d_in[12];
    const float* wq      = (const float*)d_in[13];
    const float* wk      = (const float*)d_in[14];
    const float* wv      = (const float*)d_in[15];
    const float* wo      = (const float*)d_in[16];
    const float* ln1_g   = (const float*)d_in[17];
    const float* ln1_b   = (const float*)d_in[18];
    const float* ffn_w1  = (const float*)d_in[19];
    const float* ffn_b1  = (const float*)d_in[20];
    const float* ffn_w2  = (const float*)d_in[21];
    const float* ffn_b2  = (const float*)d_in[22];
    const float* ln2_g   = (const float*)d_in[23];
    const float* ln2_b   = (const float*)d_in[24];
    const int* indexes   = (const int*)d_in[26];

    float* ws = (float*)d_ws;
    float* t0     = ws;               // 131072
    float* pooled = ws + 131072;      // 43008
    float* h      = ws + 174080;      // 696320
    float* q      = ws + 870400;      // 696320
    float* k      = ws + 1566720;     // 696320
    float* v      = ws + 2263040;     // 696320
    float* o      = ws + 2959360;     // 696320
    __hip_bfloat16* w1b = (__hip_bfloat16*)(ws + 3655680);   // 131072 bf16 (2 layers)
    __hip_bfloat16* w2b = (__hip_bfloat16*)(ws + 3721216);   // 131072 bf16 (2 layers)

    // convert FFN weights to bf16 (once per launch; deterministic)
    cvt_bf16_kernel<<<512, 256, 0, stream>>>(ffn_w1, w1b, 131072);
    cvt_bf16_kernel<<<512, 256, 0, stream>>>(ffn_w2, w2b, 131072);

    down_kernel<<<512, 256, 0, stream>>>(x, w_down, b_down, t0);
    conv_kernel<<<128, 256, 0, stream>>>(t0, pooled, conv_w, conv_b, bn_g, bn_b, bn_m, bn_v,
                                         0, 2048, 0, 512, 0, 32768);
    conv_kernel<<<32, 256, 0, stream>>>(pooled, pooled, conv_w, conv_b, bn_g, bn_b, bn_m, bn_v,
                                        1, 672, 0, 128, 512, 8192);
    conv_kernel<<<8, 256, 0, stream>>>(pooled, pooled, conv_w, conv_b, bn_g, bn_b, bn_m, bn_v,
                                       2, 672, 512, 32, 640, 2048);
    build_ln_kernel<<<1360, 256, 0, stream>>>(x, pooled, w_up, b_up, ln0_g, ln0_b, h);

    for (int l = 0; l < 2; ++l) {
        qkv_kernel<<<1020, 256, 0, stream>>>(h, wq + l * 16384, wk + l * 16384, wv + l * 16384,
                                             q, k, v);
        attn_kernel<<<340, 256, 0, stream>>>(q, k, v, o);
        o_ln_kernel<<<680, 256, 0, stream>>>(o, wo + l * 16384,
                                             ln1_g + l * 128, ln1_b + l * 128, h);
        ffn_kernel<<<1360, 256, 0, stream>>>(h, (const unsigned int*)(w1b + l * 65536),
                                             ffn_b1 + l * 512,
                                             (const unsigned int*)(w2b + l * 65536),
                                             ffn_b2 + l * 128,
                                             ln2_g + l * 128, ln2_b + l * 128, h);
    }
    gather_kernel<<<2048, 256, 0, stream>>>(h, indexes, (float*)d_out);
}

// Round 15
// 166.235 us; speedup vs baseline: 1.2095x; 1.2095x over previous
//
#include <hip/hip_runtime.h>
#include <hip/hip_bf16.h>

#define S_TOT 2720

typedef short bf16x8 __attribute__((ext_vector_type(8)));
typedef float f32x4 __attribute__((ext_vector_type(4)));

// ---------------- weight transpose+cvt: w1t[l][j][k] = bf16(w1[l][k][j])  (128x512 -> 512x128)
__global__ void cvt_w1t_kernel(const float* __restrict__ w1, __hip_bfloat16* __restrict__ w1t) {
    int id = blockIdx.x * 256 + threadIdx.x;      // 131072 (2 layers)
    int l = id >> 16, r = id & 65535;
    int j = r >> 7, k = r & 127;
    w1t[id] = __float2bfloat16(w1[l * 65536 + k * 512 + j]);
}
// ---------------- w2t[l][d][j] = bf16(w2[l][j][d])  (512x128 -> 128x512)
__global__ void cvt_w2t_kernel(const float* __restrict__ w2, __hip_bfloat16* __restrict__ w2t) {
    int id = blockIdx.x * 256 + threadIdx.x;      // 131072
    int l = id >> 16, r = id & 65535;
    int d = r >> 9, j = r & 511;
    w2t[id] = __float2bfloat16(w2[l * 65536 + j * 128 + d]);
}

// ---------------- down projection: t0[b,pos,c] = x[b,pos,:] @ w_down + b_down
__global__ void down_kernel(const float* __restrict__ x, const float* __restrict__ w,
                            const float* __restrict__ b, float* __restrict__ t0) {
    int id = blockIdx.x * 256 + threadIdx.x;     // B*2048*32 = 131072
    int c = id & 31;
    int r = id >> 5;
    const float* xr = x + (size_t)r * 128;
    float a0 = b[c], a1 = 0.f, a2 = 0.f, a3 = 0.f;
#pragma unroll
    for (int k = 0; k < 128; k += 4) {
        a0 += xr[k]     * w[(k)     * 32 + c];
        a1 += xr[k + 1] * w[(k + 1) * 32 + c];
        a2 += xr[k + 2] * w[(k + 2) * 32 + c];
        a3 += xr[k + 3] * w[(k + 3) * 32 + c];
    }
    t0[id] = (a0 + a1) + (a2 + a3);
}

// ---------------- conv (stride4,k4) + bias + BN + ELU
__global__ void conv_kernel(const float* __restrict__ in, float* __restrict__ pooled,
                            const float* __restrict__ cw, const float* __restrict__ cb,
                            const float* __restrict__ bg, const float* __restrict__ bb,
                            const float* __restrict__ bm, const float* __restrict__ bv,
                            int level, int in_bstride, int in_off, int Lout, int out_off,
                            int total) {
    int id = blockIdx.x * 256 + threadIdx.x;
    if (id >= total) return;
    int co = id & 31;
    int lo = (id >> 5) % Lout;
    int b  = id / (32 * Lout);
    const float* ib = in + (size_t)(b * in_bstride + in_off + lo * 4) * 32;
    const float* w  = cw + (size_t)(level * 32 + co) * 32 * 4;
    float acc0 = 0.f, acc1 = 0.f, acc2 = 0.f, acc3 = 0.f;
#pragma unroll
    for (int ci = 0; ci < 32; ++ci) {
        acc0 += ib[0 * 32 + ci] * w[ci * 4 + 0];
        acc1 += ib[1 * 32 + ci] * w[ci * 4 + 1];
        acc2 += ib[2 * 32 + ci] * w[ci * 4 + 2];
        acc3 += ib[3 * 32 + ci] * w[ci * 4 + 3];
    }
    float acc = ((acc0 + acc1) + (acc2 + acc3)) + cb[level * 32 + co];
    acc = (acc - bm[level * 32 + co]) * rsqrtf(bv[level * 32 + co] + 1e-5f)
          * bg[level * 32 + co] + bb[level * 32 + co];
    acc = acc > 0.f ? acc : expm1f(acc);
    pooled[(size_t)(b * 672 + out_off + lo) * 32 + co] = acc;
}

// ---------------- build h rows (copy x | pooled@w_up+b_up) fused with LN0. wave per row.
__global__ void build_ln_kernel(const float* __restrict__ x, const float* __restrict__ pooled,
                                const float* __restrict__ w_up, const float* __restrict__ b_up,
                                const float* __restrict__ g, const float* __restrict__ bta,
                                float* __restrict__ h) {
    int wave = threadIdx.x >> 6;
    int lane = threadIdx.x & 63;
    int row = blockIdx.x * 4 + wave;          // 5440 rows
    int b = row / S_TOT, s = row % S_TOT;
    float v0, v1;
    if (s < 2048) {
        const float* xr = x + (size_t)(b * 2048 + s) * 128;
        v0 = xr[lane]; v1 = xr[lane + 64];
    } else {
        int p = s - 2048;
        const float* pr = pooled + (size_t)(b * 672 + p) * 32;
        float a0 = b_up[lane], a1 = b_up[lane + 64];
        float a2 = 0.f, a3 = 0.f;
#pragma unroll
        for (int k = 0; k < 32; k += 2) {
            float p0 = pr[k], p1 = pr[k + 1];
            a0 += p0 * w_up[k * 128 + lane];
            a1 += p0 * w_up[k * 128 + lane + 64];
            a2 += p1 * w_up[(k + 1) * 128 + lane];
            a3 += p1 * w_up[(k + 1) * 128 + lane + 64];
        }
        v0 = a0 + a2; v1 = a1 + a3;
    }
    float sum = v0 + v1;
#pragma unroll
    for (int off = 32; off; off >>= 1) sum += __shfl_xor(sum, off);
    float mu = sum * (1.f / 128.f);
    float d0 = v0 - mu, d1 = v1 - mu;
    float vs = d0 * d0 + d1 * d1;
#pragma unroll
    for (int off = 32; off; off >>= 1) vs += __shfl_xor(vs, off);
    float inv = rsqrtf(vs * (1.f / 128.f) + 1e-5f);
    h[(size_t)row * 128 + lane]      = d0 * inv * g[lane]      + bta[lane];
    h[(size_t)row * 128 + lane + 64] = d1 * inv * g[lane + 64] + bta[lane + 64];
}

// ---------------- QKV: grid = 170 row-tiles x 3 mats. Block: 32 rows, one weight matrix.
// Wave owns 8 rows; lane owns 2 cols; float2 weight loads + depth-1 prefetch. (R10 config)
__global__ __launch_bounds__(256) void qkv_kernel(const float* __restrict__ H,
                                                  const float* __restrict__ wq,
                                                  const float* __restrict__ wk,
                                                  const float* __restrict__ wv,
                                                  float* __restrict__ q, float* __restrict__ k,
                                                  float* __restrict__ v) {
    __shared__ float hs[32][128];             // 16 KB
    int tid = threadIdx.x;
    int mat = blockIdx.x % 3;
    int r0  = (blockIdx.x / 3) * 32;          // 170 row-tiles
    const float* W = (mat == 0) ? wq : (mat == 1) ? wk : wv;
    float* O       = (mat == 0) ? q  : (mat == 1) ? k  : v;
    {
        const float4* src = (const float4*)(H + (size_t)r0 * 128);
        float4* dst = (float4*)hs;
#pragma unroll
        for (int i = 0; i < 4; ++i) dst[tid + i * 256] = src[tid + i * 256];
    }
    __syncthreads();
    int rbase = (tid >> 6) * 8, j0 = (tid & 63) * 2;
    float acc[8][2];
#pragma unroll
    for (int r = 0; r < 8; ++r) { acc[r][0] = 0.f; acc[r][1] = 0.f; }
    float2 wf[4], wfn[4];
#pragma unroll
    for (int kk = 0; kk < 4; ++kk) wf[kk] = *(const float2*)&W[kk * 128 + j0];
    for (int kt = 0; kt < 128; kt += 4) {
        int ktn = (kt + 4) & 127;
#pragma unroll
        for (int kk = 0; kk < 4; ++kk) wfn[kk] = *(const float2*)&W[(ktn + kk) * 128 + j0];
#pragma unroll
        for (int r = 0; r < 8; ++r) {
            float4 ha = *(const float4*)&hs[rbase + r][kt];
            acc[r][0] += ha.x * wf[0].x; acc[r][1] += ha.x * wf[0].y;
            acc[r][0] += ha.y * wf[1].x; acc[r][1] += ha.y * wf[1].y;
            acc[r][0] += ha.z * wf[2].x; acc[r][1] += ha.z * wf[2].y;
            acc[r][0] += ha.w * wf[3].x; acc[r][1] += ha.w * wf[3].y;
        }
#pragma unroll
        for (int kk = 0; kk < 4; ++kk) wf[kk] = wfn[kk];
    }
#pragma unroll
    for (int r = 0; r < 8; ++r)
        *(float2*)&O[(size_t)(r0 + rbase + r) * 128 + j0] = make_float2(acc[r][0], acc[r][1]);
}

// ---------------- sparse pyramid attention, 4 lanes per query (each owns 8 dims)
__global__ void attn_kernel(const float* __restrict__ Q, const float* __restrict__ K,
                            const float* __restrict__ V, float* __restrict__ O) {
    int id = blockIdx.x * 256 + threadIdx.x;     // 87040
    int d0 = (id & 3) * 8;
    int gid = id >> 2;                           // 21760 queries
    int i  = gid % S_TOT;
    int hh = (gid / S_TOT) & 3;
    int b  = gid / (S_TOT * 4);
    int li, s;
    if (i < 2048)      { li = 0; s = 0;    }
    else if (i < 2560) { li = 1; s = 2048; }
    else if (i < 2688) { li = 2; s = 2560; }
    else               { li = 3; s = 2688; }
    int sz = (li == 0) ? 2048 : (li == 1) ? 512 : (li == 2) ? 128 : 32;
    int pstart = (li == 0) ? 2048 : (li == 1) ? 2560 : 2688;
    int cstart = (li == 1) ? 0 : (li == 2) ? 2048 : 2560;

    const float* qp = Q + ((size_t)(b * S_TOT + i) * 128) + hh * 32 + d0;
    float4 qa = *(const float4*)qp;
    float4 qb = *(const float4*)(qp + 4);
    const float invt = 0.17677669529663687f;     // 1/sqrt(32)

    float sc[10];
    int   nj[10];
    bool  vl[10];
#pragma unroll
    for (int slot = 0; slot < 10; ++slot) {
        int j; bool valid;
        if (slot < 5)       { j = i - 2 + slot;                         valid = (j >= s) && (j < s + sz); }
        else if (slot == 5) { j = pstart + ((i - s) >> 2);              valid = (li < 3); }
        else                { j = cstart + ((i - s) << 2) + (slot - 6); valid = (li > 0); }
        nj[slot] = j; vl[slot] = valid;
        float dot = 0.f;
        if (valid) {
            const float* kp = K + ((size_t)(b * S_TOT + j) * 128) + hh * 32 + d0;
            float4 ka = *(const float4*)kp;
            float4 kb = *(const float4*)(kp + 4);
            dot = qa.x * ka.x + qa.y * ka.y + qa.z * ka.z + qa.w * ka.w
                + qb.x * kb.x + qb.y * kb.y + qb.z * kb.z + qb.w * kb.w;
        }
        dot += __shfl_xor(dot, 1);
        dot += __shfl_xor(dot, 2);
        sc[slot] = valid ? dot * invt : -1e30f;
    }
    float mx = sc[0];
#pragma unroll
    for (int slot = 1; slot < 10; ++slot) mx = fmaxf(mx, sc[slot]);
    float ssum = 0.f;
#pragma unroll
    for (int slot = 0; slot < 10; ++slot) { sc[slot] = __expf(sc[slot] - mx); ssum += sc[slot]; }
    float rinv = 1.f / ssum;
    float4 oa = {0.f, 0.f, 0.f, 0.f}, ob = {0.f, 0.f, 0.f, 0.f};
#pragma unroll
    for (int slot = 0; slot < 10; ++slot) {
        if (vl[slot]) {
            float p = sc[slot] * rinv;
            const float* vp = V + ((size_t)(b * S_TOT + nj[slot]) * 128) + hh * 32 + d0;
            float4 va = *(const float4*)vp;
            float4 vb = *(const float4*)(vp + 4);
            oa.x += p * va.x; oa.y += p * va.y; oa.z += p * va.z; oa.w += p * va.w;
            ob.x += p * vb.x; ob.y += p * vb.y; ob.z += p * vb.z; ob.w += p * vb.w;
        }
    }
    float* op = O + ((size_t)(b * S_TOT + i) * 128) + hh * 32 + d0;
    *(float4*)op = oa;
    *(float4*)(op + 4) = ob;
}

// ---------------- o-proj + residual + LN1. 340 blocks x 16 rows; wave owns 4 rows. (R10)
__global__ __launch_bounds__(256) void o_ln_kernel(const float* __restrict__ Ob,
                                                   const float* __restrict__ wo,
                                                   const float* __restrict__ g,
                                                   const float* __restrict__ bta,
                                                   float* __restrict__ h) {
    __shared__ float os[16][128];             // 8 KB
    int tid = threadIdx.x;
    int r0 = blockIdx.x * 16;                 // 340 blocks
    {
        const float4* src = (const float4*)(Ob + (size_t)r0 * 128);
        float4* dst = (float4*)os;
        dst[tid] = src[tid];
        dst[tid + 256] = src[tid + 256];
    }
    __syncthreads();
    int rbase = (tid >> 6) * 4, j0 = (tid & 63) * 2;
    float acc[4][2];
#pragma unroll
    for (int r = 0; r < 4; ++r) { acc[r][0] = 0.f; acc[r][1] = 0.f; }
    float2 wf[4], wfn[4];
#pragma unroll
    for (int kk = 0; kk < 4; ++kk) wf[kk] = *(const float2*)&wo[kk * 128 + j0];
    for (int kt = 0; kt < 128; kt += 4) {
        int ktn = (kt + 4) & 127;
#pragma unroll
        for (int kk = 0; kk < 4; ++kk) wfn[kk] = *(const float2*)&wo[(ktn + kk) * 128 + j0];
#pragma unroll
        for (int r = 0; r < 4; ++r) {
            float4 ha = *(const float4*)&os[rbase + r][kt];
            acc[r][0] += ha.x * wf[0].x; acc[r][1] += ha.x * wf[0].y;
            acc[r][0] += ha.y * wf[1].x; acc[r][1] += ha.y * wf[1].y;
            acc[r][0] += ha.z * wf[2].x; acc[r][1] += ha.z * wf[2].y;
            acc[r][0] += ha.w * wf[3].x; acc[r][1] += ha.w * wf[3].y;
        }
#pragma unroll
        for (int kk = 0; kk < 4; ++kk) wf[kk] = wfn[kk];
    }
    float g0 = g[j0], g1 = g[j0 + 1], bt0 = bta[j0], bt1 = bta[j0 + 1];
#pragma unroll
    for (int r = 0; r < 4; ++r) {
        size_t row = (size_t)(r0 + rbase + r) * 128;
        float2 res = *(const float2*)&h[row + j0];
        float v0 = acc[r][0] + res.x, v1 = acc[r][1] + res.y;
        float sum = v0 + v1;
#pragma unroll
        for (int off = 32; off; off >>= 1) sum += __shfl_xor(sum, off);
        float mu = sum * (1.f / 128.f);
        float e0 = v0 - mu, e1 = v1 - mu;
        float vs = e0 * e0 + e1 * e1;
#pragma unroll
        for (int off = 32; off; off >>= 1) vs += __shfl_xor(vs, off);
        float inv = rsqrtf(vs * (1.f / 128.f) + 1e-6f);
        *(float2*)&h[row + j0] = make_float2(e0 * inv * g0 + bt0, e1 * inv * g1 + bt1);
    }
}

// ---------------- MFMA FFN + residual + LN2. 340 blocks x 16 rows, 4 waves.
// GEMM1: 16x512x128 (32 col-tiles, 8/wave); GEMM2: 16x128x512 (8 d-tiles, 2/wave).
// Operand layout: m/n = lane&15, k = 8*(lane>>4)+i (contiguous, m92/m97-verified pattern).
// C/D: col = lane&15, row = (lane>>4)*4 + reg (m89-verified).
__global__ __launch_bounds__(256) void ffn_mfma_kernel(const float* __restrict__ H,
                                                       const __hip_bfloat16* __restrict__ w1t,
                                                       const float* __restrict__ b1,
                                                       const __hip_bfloat16* __restrict__ w2t,
                                                       const float* __restrict__ b2,
                                                       const float* __restrict__ g,
                                                       const float* __restrict__ bta,
                                                       float* __restrict__ h) {
    __shared__ __hip_bfloat16 hsb[16][136];   // h tile bf16, pad 8 (4.3 KB)
    __shared__ __hip_bfloat16 pb[16][520];    // relu(f1) bf16, pad 8 (16.6 KB)
    __shared__ float partf[16][128];          // GEMM2 fp32 out (8 KB)
    int tid = threadIdx.x;
    int r0 = blockIdx.x * 16;                 // 340 blocks
    // stage h -> bf16 LDS (thread: row=tid>>4, 8 cols)
    {
        int row = tid >> 4, c0 = (tid & 15) * 8;
        const float* src = &H[(size_t)(r0 + row) * 128 + c0];
        float4 x0 = *(const float4*)src;
        float4 x1 = *(const float4*)(src + 4);
        __hip_bfloat16* d = &hsb[row][c0];
        d[0] = __float2bfloat16(x0.x); d[1] = __float2bfloat16(x0.y);
        d[2] = __float2bfloat16(x0.z); d[3] = __float2bfloat16(x0.w);
        d[4] = __float2bfloat16(x1.x); d[5] = __float2bfloat16(x1.y);
        d[6] = __float2bfloat16(x1.z); d[7] = __float2bfloat16(x1.w);
    }
    __syncthreads();
    int lane = tid & 63, wv = tid >> 6;
    int l15 = lane & 15, grp = lane >> 4;
    // A fragments for GEMM1 (K=128 -> 4 k-slices), hoisted
    bf16x8 afr[4];
#pragma unroll
    for (int ks = 0; ks < 4; ++ks)
        afr[ks] = *(const bf16x8*)&hsb[l15][ks * 32 + grp * 8];
    // GEMM1: wave wv owns col-tiles wv*8 .. wv*8+7
#pragma unroll
    for (int t = 0; t < 8; ++t) {
        int j0 = (wv * 8 + t) * 16;
        f32x4 acc = {0.f, 0.f, 0.f, 0.f};
        const __hip_bfloat16* wb = &w1t[(size_t)(j0 + l15) * 128 + grp * 8];
#pragma unroll
        for (int ks = 0; ks < 4; ++ks) {
            bf16x8 bfr = *(const bf16x8*)&wb[ks * 32];
            acc = __builtin_amdgcn_mfma_f32_16x16x32_bf16(afr[ks], bfr, acc, 0, 0, 0);
        }
        float bv = b1[j0 + l15];
#pragma unroll
        for (int i = 0; i < 4; ++i)
            pb[grp * 4 + i][j0 + l15] = __float2bfloat16(fmaxf(acc[i] + bv, 0.f));
    }
    __syncthreads();
    // GEMM2: wave wv owns d-tiles at d0 = wv*32 and wv*32+16; K=512 -> 16 k-slices
    {
        f32x4 acc2a = {0.f, 0.f, 0.f, 0.f};
        f32x4 acc2b = {0.f, 0.f, 0.f, 0.f};
        const __hip_bfloat16* wb0 = &w2t[(size_t)(wv * 32 + l15) * 512 + grp * 8];
        const __hip_bfloat16* wb1 = &w2t[(size_t)(wv * 32 + 16 + l15) * 512 + grp * 8];
#pragma unroll
        for (int ks = 0; ks < 16; ++ks) {
            bf16x8 afr2 = *(const bf16x8*)&pb[l15][ks * 32 + grp * 8];
            bf16x8 b0 = *(const bf16x8*)&wb0[ks * 32];
            bf16x8 b1f = *(const bf16x8*)&wb1[ks * 32];
            acc2a = __builtin_amdgcn_mfma_f32_16x16x32_bf16(afr2, b0, acc2a, 0, 0, 0);
            acc2b = __builtin_amdgcn_mfma_f32_16x16x32_bf16(afr2, b1f, acc2b, 0, 0, 0);
        }
#pragma unroll
        for (int i = 0; i < 4; ++i) {
            partf[grp * 4 + i][wv * 32 + l15]      = acc2a[i];
            partf[grp * 4 + i][wv * 32 + 16 + l15] = acc2b[i];
        }
    }
    __syncthreads();
    // final: row r = tid>>4, 16 lanes x 8 d's; bias + residual + LN2 (verified block)
    {
        int r = tid >> 4, d0 = (tid & 15) * 8;
        size_t row = (size_t)(r0 + r) * 128;
        float vv[8];
        float sum = 0.f;
#pragma unroll
        for (int i = 0; i < 8; ++i) {
            int d = d0 + i;
            vv[i] = partf[r][d] + b2[d] + h[row + d];
            sum += vv[i];
        }
#pragma unroll
        for (int off = 8; off; off >>= 1) sum += __shfl_xor(sum, off);
        float mu = sum * (1.f / 128.f);
        float vs = 0.f;
#pragma unroll
        for (int i = 0; i < 8; ++i) { vv[i] -= mu; vs += vv[i] * vv[i]; }
#pragma unroll
        for (int off = 8; off; off >>= 1) vs += __shfl_xor(vs, off);
        float inv = rsqrtf(vs * (1.f / 128.f) + 1e-6f);
#pragma unroll
        for (int i = 0; i < 8; ++i) vv[i] = vv[i] * inv * g[d0 + i] + bta[d0 + i];
        *(float4*)&h[row + d0]     = make_float4(vv[0], vv[1], vv[2], vv[3]);
        *(float4*)&h[row + d0 + 4] = make_float4(vv[4], vv[5], vv[6], vv[7]);
    }
}

// ---------------- gather refer-points, float4
__global__ void gather_kernel(const float* __restrict__ H, const int* __restrict__ idx,
                              float* __restrict__ out) {
    int id = blockIdx.x * 256 + threadIdx.x;     // 524288 float4s
    int d4 = id & 31;
    int j = (id >> 5) & 3;
    int t = (id >> 7) & 2047;
    int b = id >> 18;
    int src = idx[t * 4 + j];
    ((float4*)out)[id] = *(const float4*)&H[((size_t)(b * S_TOT + src) * 128) + d4 * 4];
}

extern "C" void kernel_launch(void* const* d_in, const int* in_sizes, int n_in,
                              void* d_out, int out_size, void* d_ws, size_t ws_size,
                              hipStream_t stream) {
    (void)in_sizes; (void)n_in; (void)out_size; (void)ws_size;
    const float* x       = (const float*)d_in[0];
    const float* w_down  = (const float*)d_in[1];
    const float* b_down  = (const float*)d_in[2];
    const float* conv_w  = (const float*)d_in[3];
    const float* conv_b  = (const float*)d_in[4];
    const float* bn_g    = (const float*)d_in[5];
    const float* bn_b    = (const float*)d_in[6];
    const float* bn_m    = (const float*)d_in[7];
    const float* bn_v    = (const float*)d_in[8];
    const float* w_up    = (const float*)d_in[9];
    const float* b_up    = (const float*)d_in[10];
    const float* ln0_g   = (const float*)d_in[11];
    const float* ln0_b   = (const float*)d_in[12];
    const float* wq      = (const float*)d_in[13];
    const float* wk      = (const float*)d_in[14];
    const float* wv      = (const float*)d_in[15];
    const float* wo      = (const float*)d_in[16];
    const float* ln1_g   = (const float*)d_in[17];
    const float* ln1_b   = (const float*)d_in[18];
    const float* ffn_w1  = (const float*)d_in[19];
    const float* ffn_b1  = (const float*)d_in[20];
    const float* ffn_w2  = (const float*)d_in[21];
    const float* ffn_b2  = (const float*)d_in[22];
    const float* ln2_g   = (const float*)d_in[23];
    const float* ln2_b   = (const float*)d_in[24];
    const int* indexes   = (const int*)d_in[26];

    float* ws = (float*)d_ws;
    float* t0     = ws;               // 131072
    float* pooled = ws + 131072;      // 43008
    float* h      = ws + 174080;      // 696320
    float* q      = ws + 870400;      // 696320
    float* k      = ws + 1566720;     // 696320
    float* v      = ws + 2263040;     // 696320
    float* o      = ws + 2959360;     // 696320
    __hip_bfloat16* w1t = (__hip_bfloat16*)(ws + 3655680);   // 131072 bf16 (2 layers)
    __hip_bfloat16* w2t = (__hip_bfloat16*)(ws + 3721216);   // 131072 bf16 (2 layers)

    cvt_w1t_kernel<<<512, 256, 0, stream>>>(ffn_w1, w1t);
    cvt_w2t_kernel<<<512, 256, 0, stream>>>(ffn_w2, w2t);

    down_kernel<<<512, 256, 0, stream>>>(x, w_down, b_down, t0);
    conv_kernel<<<128, 256, 0, stream>>>(t0, pooled, conv_w, conv_b, bn_g, bn_b, bn_m, bn_v,
                                         0, 2048, 0, 512, 0, 32768);
    conv_kernel<<<32, 256, 0, stream>>>(pooled, pooled, conv_w, conv_b, bn_g, bn_b, bn_m, bn_v,
                                        1, 672, 0, 128, 512, 8192);
    conv_kernel<<<8, 256, 0, stream>>>(pooled, pooled, conv_w, conv_b, bn_g, bn_b, bn_m, bn_v,
                                       2, 672, 512, 32, 640, 2048);
    build_ln_kernel<<<1360, 256, 0, stream>>>(x, pooled, w_up, b_up, ln0_g, ln0_b, h);

    for (int l = 0; l < 2; ++l) {
        qkv_kernel<<<510, 256, 0, stream>>>(h, wq + l * 16384, wk + l * 16384, wv + l * 16384,
                                            q, k, v);
        attn_kernel<<<340, 256, 0, stream>>>(q, k, v, o);
        o_ln_kernel<<<340, 256, 0, stream>>>(o, wo + l * 16384,
                                             ln1_g + l * 128, ln1_b + l * 128, h);
        ffn_mfma_kernel<<<340, 256, 0, stream>>>(h, w1t + l * 65536, ffn_b1 + l * 512,
                                                 w2t + l * 65536, ffn_b2 + l * 128,
                                                 ln2_g + l * 128, ln2_b + l * 128, h);
    }
    gather_kernel<<<2048, 256, 0, stream>>>(h, indexes, (float*)d_out);
}

// Round 16
// 138.308 us; speedup vs baseline: 1.4538x; 1.2019x over previous
//
#include <hip/hip_runtime.h>
#include <hip/hip_bf16.h>

#define S_TOT 2720

typedef short bf16x8 __attribute__((ext_vector_type(8)));
typedef float f32x4 __attribute__((ext_vector_type(4)));

// ---------------- weight transpose+cvt kernels (run once per launch, into d_ws)
// w1t[l][j][k] = bf16(w1[l][k][j])  (128x512 -> 512x128)
__global__ void cvt_w1t_kernel(const float* __restrict__ w1, __hip_bfloat16* __restrict__ w1t) {
    int id = blockIdx.x * 256 + threadIdx.x;      // 131072 (2 layers)
    int l = id >> 16, r = id & 65535;
    int j = r >> 7, k = r & 127;
    w1t[id] = __float2bfloat16(w1[l * 65536 + k * 512 + j]);
}
// w2t[l][d][j] = bf16(w2[l][j][d])  (512x128 -> 128x512)
__global__ void cvt_w2t_kernel(const float* __restrict__ w2, __hip_bfloat16* __restrict__ w2t) {
    int id = blockIdx.x * 256 + threadIdx.x;      // 131072
    int l = id >> 16, r = id & 65535;
    int d = r >> 9, j = r & 511;
    w2t[id] = __float2bfloat16(w2[l * 65536 + j * 128 + d]);
}
// wqkvt[l][m][j][k] = bf16(W_m[l][k][j]), m in {q,k,v}  (each 128x128)
__global__ void cvt_qkvt_kernel(const float* __restrict__ wq, const float* __restrict__ wk,
                                const float* __restrict__ wv, __hip_bfloat16* __restrict__ out) {
    int id = blockIdx.x * 256 + threadIdx.x;      // 98304 (2 layers x 3 x 16384)
    int l = id / 49152, r = id % 49152;
    int m = r >> 14, rr = r & 16383;
    int j = rr >> 7, k = rr & 127;
    const float* W = (m == 0) ? wq : (m == 1) ? wk : wv;
    out[id] = __float2bfloat16(W[l * 16384 + k * 128 + j]);
}
// wot[l][j][k] = bf16(wo[l][k][j])  (128x128)
__global__ void cvt_wot_kernel(const float* __restrict__ wo, __hip_bfloat16* __restrict__ out) {
    int id = blockIdx.x * 256 + threadIdx.x;      // 32768
    int l = id >> 14, r = id & 16383;
    int j = r >> 7, k = r & 127;
    out[id] = __float2bfloat16(wo[l * 16384 + k * 128 + j]);
}

// ---------------- down projection: t0[b,pos,c] = x[b,pos,:] @ w_down + b_down
__global__ void down_kernel(const float* __restrict__ x, const float* __restrict__ w,
                            const float* __restrict__ b, float* __restrict__ t0) {
    int id = blockIdx.x * 256 + threadIdx.x;     // B*2048*32 = 131072
    int c = id & 31;
    int r = id >> 5;
    const float* xr = x + (size_t)r * 128;
    float a0 = b[c], a1 = 0.f, a2 = 0.f, a3 = 0.f;
#pragma unroll
    for (int k = 0; k < 128; k += 4) {
        a0 += xr[k]     * w[(k)     * 32 + c];
        a1 += xr[k + 1] * w[(k + 1) * 32 + c];
        a2 += xr[k + 2] * w[(k + 2) * 32 + c];
        a3 += xr[k + 3] * w[(k + 3) * 32 + c];
    }
    t0[id] = (a0 + a1) + (a2 + a3);
}

// ---------------- conv (stride4,k4) + bias + BN + ELU
__global__ void conv_kernel(const float* __restrict__ in, float* __restrict__ pooled,
                            const float* __restrict__ cw, const float* __restrict__ cb,
                            const float* __restrict__ bg, const float* __restrict__ bb,
                            const float* __restrict__ bm, const float* __restrict__ bv,
                            int level, int in_bstride, int in_off, int Lout, int out_off,
                            int total) {
    int id = blockIdx.x * 256 + threadIdx.x;
    if (id >= total) return;
    int co = id & 31;
    int lo = (id >> 5) % Lout;
    int b  = id / (32 * Lout);
    const float* ib = in + (size_t)(b * in_bstride + in_off + lo * 4) * 32;
    const float* w  = cw + (size_t)(level * 32 + co) * 32 * 4;
    float acc0 = 0.f, acc1 = 0.f, acc2 = 0.f, acc3 = 0.f;
#pragma unroll
    for (int ci = 0; ci < 32; ++ci) {
        acc0 += ib[0 * 32 + ci] * w[ci * 4 + 0];
        acc1 += ib[1 * 32 + ci] * w[ci * 4 + 1];
        acc2 += ib[2 * 32 + ci] * w[ci * 4 + 2];
        acc3 += ib[3 * 32 + ci] * w[ci * 4 + 3];
    }
    float acc = ((acc0 + acc1) + (acc2 + acc3)) + cb[level * 32 + co];
    acc = (acc - bm[level * 32 + co]) * rsqrtf(bv[level * 32 + co] + 1e-5f)
          * bg[level * 32 + co] + bb[level * 32 + co];
    acc = acc > 0.f ? acc : expm1f(acc);
    pooled[(size_t)(b * 672 + out_off + lo) * 32 + co] = acc;
}

// ---------------- build h rows (copy x | pooled@w_up+b_up) fused with LN0. wave per row.
__global__ void build_ln_kernel(const float* __restrict__ x, const float* __restrict__ pooled,
                                const float* __restrict__ w_up, const float* __restrict__ b_up,
                                const float* __restrict__ g, const float* __restrict__ bta,
                                float* __restrict__ h) {
    int wave = threadIdx.x >> 6;
    int lane = threadIdx.x & 63;
    int row = blockIdx.x * 4 + wave;          // 5440 rows
    int b = row / S_TOT, s = row % S_TOT;
    float v0, v1;
    if (s < 2048) {
        const float* xr = x + (size_t)(b * 2048 + s) * 128;
        v0 = xr[lane]; v1 = xr[lane + 64];
    } else {
        int p = s - 2048;
        const float* pr = pooled + (size_t)(b * 672 + p) * 32;
        float a0 = b_up[lane], a1 = b_up[lane + 64];
        float a2 = 0.f, a3 = 0.f;
#pragma unroll
        for (int k = 0; k < 32; k += 2) {
            float p0 = pr[k], p1 = pr[k + 1];
            a0 += p0 * w_up[k * 128 + lane];
            a1 += p0 * w_up[k * 128 + lane + 64];
            a2 += p1 * w_up[(k + 1) * 128 + lane];
            a3 += p1 * w_up[(k + 1) * 128 + lane + 64];
        }
        v0 = a0 + a2; v1 = a1 + a3;
    }
    float sum = v0 + v1;
#pragma unroll
    for (int off = 32; off; off >>= 1) sum += __shfl_xor(sum, off);
    float mu = sum * (1.f / 128.f);
    float d0 = v0 - mu, d1 = v1 - mu;
    float vs = d0 * d0 + d1 * d1;
#pragma unroll
    for (int off = 32; off; off >>= 1) vs += __shfl_xor(vs, off);
    float inv = rsqrtf(vs * (1.f / 128.f) + 1e-5f);
    h[(size_t)row * 128 + lane]      = d0 * inv * g[lane]      + bta[lane];
    h[(size_t)row * 128 + lane + 64] = d1 * inv * g[lane + 64] + bta[lane + 64];
}

// ---------------- MFMA QKV: 340 blocks x 16 rows, 4 waves x 6 col-tiles (3 mats x 8 tiles).
// Operand layout: m/n = lane&15, k = 8*(lane>>4)+i; C/D: col=lane&15, row=(lane>>4)*4+reg.
__global__ __launch_bounds__(256) void qkv_mfma_kernel(const float* __restrict__ H,
                                                       const __hip_bfloat16* __restrict__ wqkvt,
                                                       float* __restrict__ q,
                                                       float* __restrict__ k,
                                                       float* __restrict__ v) {
    __shared__ __hip_bfloat16 hsb[16][136];
    int tid = threadIdx.x;
    int r0 = blockIdx.x * 16;                 // 340 blocks
    {
        int row = tid >> 4, c0 = (tid & 15) * 8;
        const float* src = &H[(size_t)(r0 + row) * 128 + c0];
        float4 x0 = *(const float4*)src;
        float4 x1 = *(const float4*)(src + 4);
        __hip_bfloat16* d = &hsb[row][c0];
        d[0] = __float2bfloat16(x0.x); d[1] = __float2bfloat16(x0.y);
        d[2] = __float2bfloat16(x0.z); d[3] = __float2bfloat16(x0.w);
        d[4] = __float2bfloat16(x1.x); d[5] = __float2bfloat16(x1.y);
        d[6] = __float2bfloat16(x1.z); d[7] = __float2bfloat16(x1.w);
    }
    __syncthreads();
    int lane = tid & 63, wv = tid >> 6;
    int l15 = lane & 15, grp = lane >> 4;
    bf16x8 afr[4];
#pragma unroll
    for (int ks = 0; ks < 4; ++ks)
        afr[ks] = *(const bf16x8*)&hsb[l15][ks * 32 + grp * 8];
    float* O[3] = {q, k, v};
#pragma unroll
    for (int t = 0; t < 6; ++t) {
        int gt = wv * 6 + t;                  // 0..23
        int mat = gt >> 3, jj = gt & 7;
        int j0 = jj * 16;
        f32x4 acc = {0.f, 0.f, 0.f, 0.f};
        const __hip_bfloat16* wb = &wqkvt[(size_t)(mat * 128 + j0 + l15) * 128 + grp * 8];
#pragma unroll
        for (int ks = 0; ks < 4; ++ks) {
            bf16x8 bfr = *(const bf16x8*)&wb[ks * 32];
            acc = __builtin_amdgcn_mfma_f32_16x16x32_bf16(afr[ks], bfr, acc, 0, 0, 0);
        }
        float* Om = O[mat];
#pragma unroll
        for (int i = 0; i < 4; ++i)
            Om[(size_t)(r0 + grp * 4 + i) * 128 + j0 + l15] = acc[i];
    }
}

// ---------------- sparse pyramid attention, 4 lanes per query (each owns 8 dims)
__global__ void attn_kernel(const float* __restrict__ Q, const float* __restrict__ K,
                            const float* __restrict__ V, float* __restrict__ O) {
    int id = blockIdx.x * 256 + threadIdx.x;     // 87040
    int d0 = (id & 3) * 8;
    int gid = id >> 2;                           // 21760 queries
    int i  = gid % S_TOT;
    int hh = (gid / S_TOT) & 3;
    int b  = gid / (S_TOT * 4);
    int li, s;
    if (i < 2048)      { li = 0; s = 0;    }
    else if (i < 2560) { li = 1; s = 2048; }
    else if (i < 2688) { li = 2; s = 2560; }
    else               { li = 3; s = 2688; }
    int sz = (li == 0) ? 2048 : (li == 1) ? 512 : (li == 2) ? 128 : 32;
    int pstart = (li == 0) ? 2048 : (li == 1) ? 2560 : 2688;
    int cstart = (li == 1) ? 0 : (li == 2) ? 2048 : 2560;

    const float* qp = Q + ((size_t)(b * S_TOT + i) * 128) + hh * 32 + d0;
    float4 qa = *(const float4*)qp;
    float4 qb = *(const float4*)(qp + 4);
    const float invt = 0.17677669529663687f;     // 1/sqrt(32)

    float sc[10];
    int   nj[10];
    bool  vl[10];
#pragma unroll
    for (int slot = 0; slot < 10; ++slot) {
        int j; bool valid;
        if (slot < 5)       { j = i - 2 + slot;                         valid = (j >= s) && (j < s + sz); }
        else if (slot == 5) { j = pstart + ((i - s) >> 2);              valid = (li < 3); }
        else                { j = cstart + ((i - s) << 2) + (slot - 6); valid = (li > 0); }
        nj[slot] = j; vl[slot] = valid;
        float dot = 0.f;
        if (valid) {
            const float* kp = K + ((size_t)(b * S_TOT + j) * 128) + hh * 32 + d0;
            float4 ka = *(const float4*)kp;
            float4 kb = *(const float4*)(kp + 4);
            dot = qa.x * ka.x + qa.y * ka.y + qa.z * ka.z + qa.w * ka.w
                + qb.x * kb.x + qb.y * kb.y + qb.z * kb.z + qb.w * kb.w;
        }
        dot += __shfl_xor(dot, 1);
        dot += __shfl_xor(dot, 2);
        sc[slot] = valid ? dot * invt : -1e30f;
    }
    float mx = sc[0];
#pragma unroll
    for (int slot = 1; slot < 10; ++slot) mx = fmaxf(mx, sc[slot]);
    float ssum = 0.f;
#pragma unroll
    for (int slot = 0; slot < 10; ++slot) { sc[slot] = __expf(sc[slot] - mx); ssum += sc[slot]; }
    float rinv = 1.f / ssum;
    float4 oa = {0.f, 0.f, 0.f, 0.f}, ob = {0.f, 0.f, 0.f, 0.f};
#pragma unroll
    for (int slot = 0; slot < 10; ++slot) {
        if (vl[slot]) {
            float p = sc[slot] * rinv;
            const float* vp = V + ((size_t)(b * S_TOT + nj[slot]) * 128) + hh * 32 + d0;
            float4 va = *(const float4*)vp;
            float4 vb = *(const float4*)(vp + 4);
            oa.x += p * va.x; oa.y += p * va.y; oa.z += p * va.z; oa.w += p * va.w;
            ob.x += p * vb.x; ob.y += p * vb.y; ob.z += p * vb.z; ob.w += p * vb.w;
        }
    }
    float* op = O + ((size_t)(b * S_TOT + i) * 128) + hh * 32 + d0;
    *(float4*)op = oa;
    *(float4*)(op + 4) = ob;
}

// ---------------- MFMA o-proj + residual + LN1. 340 blocks x 16 rows, 4 waves x 2 col-tiles.
__global__ __launch_bounds__(256) void o_ln_mfma_kernel(const float* __restrict__ Ob,
                                                        const __hip_bfloat16* __restrict__ wot,
                                                        const float* __restrict__ g,
                                                        const float* __restrict__ bta,
                                                        float* __restrict__ h) {
    __shared__ __hip_bfloat16 osb[16][136];
    __shared__ float partf[16][128];
    int tid = threadIdx.x;
    int r0 = blockIdx.x * 16;                 // 340 blocks
    {
        int row = tid >> 4, c0 = (tid & 15) * 8;
        const float* src = &Ob[(size_t)(r0 + row) * 128 + c0];
        float4 x0 = *(const float4*)src;
        float4 x1 = *(const float4*)(src + 4);
        __hip_bfloat16* d = &osb[row][c0];
        d[0] = __float2bfloat16(x0.x); d[1] = __float2bfloat16(x0.y);
        d[2] = __float2bfloat16(x0.z); d[3] = __float2bfloat16(x0.w);
        d[4] = __float2bfloat16(x1.x); d[5] = __float2bfloat16(x1.y);
        d[6] = __float2bfloat16(x1.z); d[7] = __float2bfloat16(x1.w);
    }
    __syncthreads();
    int lane = tid & 63, wv = tid >> 6;
    int l15 = lane & 15, grp = lane >> 4;
    bf16x8 afr[4];
#pragma unroll
    for (int ks = 0; ks < 4; ++ks)
        afr[ks] = *(const bf16x8*)&osb[l15][ks * 32 + grp * 8];
#pragma unroll
    for (int t = 0; t < 2; ++t) {
        int j0 = (wv * 2 + t) * 16;
        f32x4 acc = {0.f, 0.f, 0.f, 0.f};
        const __hip_bfloat16* wb = &wot[(size_t)(j0 + l15) * 128 + grp * 8];
#pragma unroll
        for (int ks = 0; ks < 4; ++ks) {
            bf16x8 bfr = *(const bf16x8*)&wb[ks * 32];
            acc = __builtin_amdgcn_mfma_f32_16x16x32_bf16(afr[ks], bfr, acc, 0, 0, 0);
        }
#pragma unroll
        for (int i = 0; i < 4; ++i)
            partf[grp * 4 + i][j0 + l15] = acc[i];
    }
    __syncthreads();
    // final: residual + LN1 (16 lanes per row x 8 d's)
    {
        int r = tid >> 4, d0 = (tid & 15) * 8;
        size_t row = (size_t)(r0 + r) * 128;
        float vv[8];
        float sum = 0.f;
#pragma unroll
        for (int i = 0; i < 8; ++i) {
            int d = d0 + i;
            vv[i] = partf[r][d] + h[row + d];
            sum += vv[i];
        }
#pragma unroll
        for (int off = 8; off; off >>= 1) sum += __shfl_xor(sum, off);
        float mu = sum * (1.f / 128.f);
        float vs = 0.f;
#pragma unroll
        for (int i = 0; i < 8; ++i) { vv[i] -= mu; vs += vv[i] * vv[i]; }
#pragma unroll
        for (int off = 8; off; off >>= 1) vs += __shfl_xor(vs, off);
        float inv = rsqrtf(vs * (1.f / 128.f) + 1e-6f);
#pragma unroll
        for (int i = 0; i < 8; ++i) vv[i] = vv[i] * inv * g[d0 + i] + bta[d0 + i];
        *(float4*)&h[row + d0]     = make_float4(vv[0], vv[1], vv[2], vv[3]);
        *(float4*)&h[row + d0 + 4] = make_float4(vv[4], vv[5], vv[6], vv[7]);
    }
}

// ---------------- MFMA FFN + residual + LN2. 340 blocks x 16 rows, 4 waves. (R15, verified)
__global__ __launch_bounds__(256) void ffn_mfma_kernel(const float* __restrict__ H,
                                                       const __hip_bfloat16* __restrict__ w1t,
                                                       const float* __restrict__ b1,
                                                       const __hip_bfloat16* __restrict__ w2t,
                                                       const float* __restrict__ b2,
                                                       const float* __restrict__ g,
                                                       const float* __restrict__ bta,
                                                       float* __restrict__ h) {
    __shared__ __hip_bfloat16 hsb[16][136];
    __shared__ __hip_bfloat16 pb[16][520];
    __shared__ float partf[16][128];
    int tid = threadIdx.x;
    int r0 = blockIdx.x * 16;                 // 340 blocks
    {
        int row = tid >> 4, c0 = (tid & 15) * 8;
        const float* src = &H[(size_t)(r0 + row) * 128 + c0];
        float4 x0 = *(const float4*)src;
        float4 x1 = *(const float4*)(src + 4);
        __hip_bfloat16* d = &hsb[row][c0];
        d[0] = __float2bfloat16(x0.x); d[1] = __float2bfloat16(x0.y);
        d[2] = __float2bfloat16(x0.z); d[3] = __float2bfloat16(x0.w);
        d[4] = __float2bfloat16(x1.x); d[5] = __float2bfloat16(x1.y);
        d[6] = __float2bfloat16(x1.z); d[7] = __float2bfloat16(x1.w);
    }
    __syncthreads();
    int lane = tid & 63, wv = tid >> 6;
    int l15 = lane & 15, grp = lane >> 4;
    bf16x8 afr[4];
#pragma unroll
    for (int ks = 0; ks < 4; ++ks)
        afr[ks] = *(const bf16x8*)&hsb[l15][ks * 32 + grp * 8];
#pragma unroll
    for (int t = 0; t < 8; ++t) {
        int j0 = (wv * 8 + t) * 16;
        f32x4 acc = {0.f, 0.f, 0.f, 0.f};
        const __hip_bfloat16* wb = &w1t[(size_t)(j0 + l15) * 128 + grp * 8];
#pragma unroll
        for (int ks = 0; ks < 4; ++ks) {
            bf16x8 bfr = *(const bf16x8*)&wb[ks * 32];
            acc = __builtin_amdgcn_mfma_f32_16x16x32_bf16(afr[ks], bfr, acc, 0, 0, 0);
        }
        float bv = b1[j0 + l15];
#pragma unroll
        for (int i = 0; i < 4; ++i)
            pb[grp * 4 + i][j0 + l15] = __float2bfloat16(fmaxf(acc[i] + bv, 0.f));
    }
    __syncthreads();
    {
        f32x4 acc2a = {0.f, 0.f, 0.f, 0.f};
        f32x4 acc2b = {0.f, 0.f, 0.f, 0.f};
        const __hip_bfloat16* wb0 = &w2t[(size_t)(wv * 32 + l15) * 512 + grp * 8];
        const __hip_bfloat16* wb1 = &w2t[(size_t)(wv * 32 + 16 + l15) * 512 + grp * 8];
#pragma unroll
        for (int ks = 0; ks < 16; ++ks) {
            bf16x8 afr2 = *(const bf16x8*)&pb[l15][ks * 32 + grp * 8];
            bf16x8 b0 = *(const bf16x8*)&wb0[ks * 32];
            bf16x8 b1f = *(const bf16x8*)&wb1[ks * 32];
            acc2a = __builtin_amdgcn_mfma_f32_16x16x32_bf16(afr2, b0, acc2a, 0, 0, 0);
            acc2b = __builtin_amdgcn_mfma_f32_16x16x32_bf16(afr2, b1f, acc2b, 0, 0, 0);
        }
#pragma unroll
        for (int i = 0; i < 4; ++i) {
            partf[grp * 4 + i][wv * 32 + l15]      = acc2a[i];
            partf[grp * 4 + i][wv * 32 + 16 + l15] = acc2b[i];
        }
    }
    __syncthreads();
    {
        int r = tid >> 4, d0 = (tid & 15) * 8;
        size_t row = (size_t)(r0 + r) * 128;
        float vv[8];
        float sum = 0.f;
#pragma unroll
        for (int i = 0; i < 8; ++i) {
            int d = d0 + i;
            vv[i] = partf[r][d] + b2[d] + h[row + d];
            sum += vv[i];
        }
#pragma unroll
        for (int off = 8; off; off >>= 1) sum += __shfl_xor(sum, off);
        float mu = sum * (1.f / 128.f);
        float vs = 0.f;
#pragma unroll
        for (int i = 0; i < 8; ++i) { vv[i] -= mu; vs += vv[i] * vv[i]; }
#pragma unroll
        for (int off = 8; off; off >>= 1) vs += __shfl_xor(vs, off);
        float inv = rsqrtf(vs * (1.f / 128.f) + 1e-6f);
#pragma unroll
        for (int i = 0; i < 8; ++i) vv[i] = vv[i] * inv * g[d0 + i] + bta[d0 + i];
        *(float4*)&h[row + d0]     = make_float4(vv[0], vv[1], vv[2], vv[3]);
        *(float4*)&h[row + d0 + 4] = make_float4(vv[4], vv[5], vv[6], vv[7]);
    }
}

// ---------------- gather refer-points, float4
__global__ void gather_kernel(const float* __restrict__ H, const int* __restrict__ idx,
                              float* __restrict__ out) {
    int id = blockIdx.x * 256 + threadIdx.x;     // 524288 float4s
    int d4 = id & 31;
    int j = (id >> 5) & 3;
    int t = (id >> 7) & 2047;
    int b = id >> 18;
    int src = idx[t * 4 + j];
    ((float4*)out)[id] = *(const float4*)&H[((size_t)(b * S_TOT + src) * 128) + d4 * 4];
}

extern "C" void kernel_launch(void* const* d_in, const int* in_sizes, int n_in,
                              void* d_out, int out_size, void* d_ws, size_t ws_size,
                              hipStream_t stream) {
    (void)in_sizes; (void)n_in; (void)out_size; (void)ws_size;
    const float* x       = (const float*)d_in[0];
    const float* w_down  = (const float*)d_in[1];
    const float* b_down  = (const float*)d_in[2];
    const float* conv_w  = (const float*)d_in[3];
    const float* conv_b  = (const float*)d_in[4];
    const float* bn_g    = (const float*)d_in[5];
    const float* bn_b    = (const float*)d_in[6];
    const float* bn_m    = (const float*)d_in[7];
    const float* bn_v    = (const float*)d_in[8];
    const float* w_up    = (const float*)d_in[9];
    const float* b_up    = (const float*)d_in[10];
    const float* ln0_g   = (const float*)d_in[11];
    const float* ln0_b   = (const float*)d_in[12];
    const float* wq      = (const float*)d_in[13];
    const float* wk      = (const float*)d_in[14];
    const float* wv      = (const float*)d_in[15];
    const float* wo      = (const float*)d_in[16];
    const float* ln1_g   = (const float*)d_in[17];
    const float* ln1_b   = (const float*)d_in[18];
    const float* ffn_w1  = (const float*)d_in[19];
    const float* ffn_b1  = (const float*)d_in[20];
    const float* ffn_w2  = (const float*)d_in[21];
    const float* ffn_b2  = (const float*)d_in[22];
    const float* ln2_g   = (const float*)d_in[23];
    const float* ln2_b   = (const float*)d_in[24];
    const int* indexes   = (const int*)d_in[26];

    float* ws = (float*)d_ws;
    float* t0     = ws;               // 131072
    float* pooled = ws + 131072;      // 43008
    float* h      = ws + 174080;      // 696320
    float* q      = ws + 870400;      // 696320
    float* k      = ws + 1566720;     // 696320
    float* v      = ws + 2263040;     // 696320
    float* o      = ws + 2959360;     // 696320
    __hip_bfloat16* w1t   = (__hip_bfloat16*)(ws + 3655680);  // 131072 bf16
    __hip_bfloat16* w2t   = (__hip_bfloat16*)(ws + 3721216);  // 131072 bf16
    __hip_bfloat16* wqkvt = (__hip_bfloat16*)(ws + 3786752);  // 98304 bf16
    __hip_bfloat16* wot   = (__hip_bfloat16*)(ws + 3835904);  // 32768 bf16

    cvt_w1t_kernel<<<512, 256, 0, stream>>>(ffn_w1, w1t);
    cvt_w2t_kernel<<<512, 256, 0, stream>>>(ffn_w2, w2t);
    cvt_qkvt_kernel<<<384, 256, 0, stream>>>(wq, wk, wv, wqkvt);
    cvt_wot_kernel<<<128, 256, 0, stream>>>(wo, wot);

    down_kernel<<<512, 256, 0, stream>>>(x, w_down, b_down, t0);
    conv_kernel<<<128, 256, 0, stream>>>(t0, pooled, conv_w, conv_b, bn_g, bn_b, bn_m, bn_v,
                                         0, 2048, 0, 512, 0, 32768);
    conv_kernel<<<32, 256, 0, stream>>>(pooled, pooled, conv_w, conv_b, bn_g, bn_b, bn_m, bn_v,
                                        1, 672, 0, 128, 512, 8192);
    conv_kernel<<<8, 256, 0, stream>>>(pooled, pooled, conv_w, conv_b, bn_g, bn_b, bn_m, bn_v,
                                       2, 672, 512, 32, 640, 2048);
    build_ln_kernel<<<1360, 256, 0, stream>>>(x, pooled, w_up, b_up, ln0_g, ln0_b, h);

    for (int l = 0; l < 2; ++l) {
        qkv_mfma_kernel<<<340, 256, 0, stream>>>(h, wqkvt + l * 49152, q, k, v);
        attn_kernel<<<340, 256, 0, stream>>>(q, k, v, o);
        o_ln_mfma_kernel<<<340, 256, 0, stream>>>(o, wot + l * 16384,
                                                  ln1_g + l * 128, ln1_b + l * 128, h);
        ffn_mfma_kernel<<<340, 256, 0, stream>>>(h, w1t + l * 65536, ffn_b1 + l * 512,
                                                 w2t + l * 65536, ffn_b2 + l * 128,
                                                 ln2_g + l * 128, ln2_b + l * 128, h);
    }
    gather_kernel<<<2048, 256, 0, stream>>>(h, indexes, (float*)d_out);
}

// Round 17
// 127.123 us; speedup vs baseline: 1.5817x; 1.0880x over previous
//
#include <hip/hip_runtime.h>
#include <hip/hip_bf16.h>

#define S_TOT 2720

typedef short bf16x8 __attribute__((ext_vector_type(8)));
typedef float f32x4 __attribute__((ext_vector_type(4)));

// ---------------- all weight transpose+cvt in one kernel (393216 elems = 1536 blocks)
// layout in ws: w1t[2][512][128] | w2t[2][128][512] | wqkvt[2][3][128][128] | wot[2][128][128]
__global__ void cvt_all_kernel(const float* __restrict__ w1, const float* __restrict__ w2,
                               const float* __restrict__ wq, const float* __restrict__ wk,
                               const float* __restrict__ wv, const float* __restrict__ wo,
                               __hip_bfloat16* __restrict__ out) {
    int id = blockIdx.x * 256 + threadIdx.x;
    if (id < 131072) {                        // w1t[l][j][k] = w1[l][k][j] (128x512 -> T)
        int l = id >> 16, r = id & 65535;
        int j = r >> 7, k = r & 127;
        out[id] = __float2bfloat16(w1[l * 65536 + k * 512 + j]);
    } else if (id < 262144) {                 // w2t[l][d][j] = w2[l][j][d]
        int t = id - 131072;
        int l = t >> 16, r = t & 65535;
        int d = r >> 9, j = r & 511;
        out[id] = __float2bfloat16(w2[l * 65536 + j * 128 + d]);
    } else if (id < 360448) {                 // wqkvt[l][m][j][k] = W_m[l][k][j]
        int t = id - 262144;
        int l = t / 49152, r = t % 49152;
        int m = r >> 14, rr = r & 16383;
        int j = rr >> 7, k = rr & 127;
        const float* W = (m == 0) ? wq : (m == 1) ? wk : wv;
        out[id] = __float2bfloat16(W[l * 16384 + k * 128 + j]);
    } else {                                  // wot[l][j][k] = wo[l][k][j]
        int t = id - 360448;
        int l = t >> 14, r = t & 16383;
        int j = r >> 7, k = r & 127;
        out[id] = __float2bfloat16(wo[l * 16384 + k * 128 + j]);
    }
}

// ---------------- down projection: t0[b,pos,c] = x[b,pos,:] @ w_down + b_down
__global__ void down_kernel(const float* __restrict__ x, const float* __restrict__ w,
                            const float* __restrict__ b, float* __restrict__ t0) {
    int id = blockIdx.x * 256 + threadIdx.x;     // B*2048*32 = 131072
    int c = id & 31;
    int r = id >> 5;
    const float* xr = x + (size_t)r * 128;
    float a0 = b[c], a1 = 0.f, a2 = 0.f, a3 = 0.f;
#pragma unroll
    for (int k = 0; k < 128; k += 4) {
        a0 += xr[k]     * w[(k)     * 32 + c];
        a1 += xr[k + 1] * w[(k + 1) * 32 + c];
        a2 += xr[k + 2] * w[(k + 2) * 32 + c];
        a3 += xr[k + 3] * w[(k + 3) * 32 + c];
    }
    t0[id] = (a0 + a1) + (a2 + a3);
}

// ---------------- conv (stride4,k4) + bias + BN + ELU
__global__ void conv_kernel(const float* __restrict__ in, float* __restrict__ pooled,
                            const float* __restrict__ cw, const float* __restrict__ cb,
                            const float* __restrict__ bg, const float* __restrict__ bb,
                            const float* __restrict__ bm, const float* __restrict__ bv,
                            int level, int in_bstride, int in_off, int Lout, int out_off,
                            int total) {
    int id = blockIdx.x * 256 + threadIdx.x;
    if (id >= total) return;
    int co = id & 31;
    int lo = (id >> 5) % Lout;
    int b  = id / (32 * Lout);
    const float* ib = in + (size_t)(b * in_bstride + in_off + lo * 4) * 32;
    const float* w  = cw + (size_t)(level * 32 + co) * 32 * 4;
    float acc0 = 0.f, acc1 = 0.f, acc2 = 0.f, acc3 = 0.f;
#pragma unroll
    for (int ci = 0; ci < 32; ++ci) {
        acc0 += ib[0 * 32 + ci] * w[ci * 4 + 0];
        acc1 += ib[1 * 32 + ci] * w[ci * 4 + 1];
        acc2 += ib[2 * 32 + ci] * w[ci * 4 + 2];
        acc3 += ib[3 * 32 + ci] * w[ci * 4 + 3];
    }
    float acc = ((acc0 + acc1) + (acc2 + acc3)) + cb[level * 32 + co];
    acc = (acc - bm[level * 32 + co]) * rsqrtf(bv[level * 32 + co] + 1e-5f)
          * bg[level * 32 + co] + bb[level * 32 + co];
    acc = acc > 0.f ? acc : expm1f(acc);
    pooled[(size_t)(b * 672 + out_off + lo) * 32 + co] = acc;
}

// ---------------- build h rows (copy x | pooled@w_up+b_up) fused with LN0. wave per row.
__global__ void build_ln_kernel(const float* __restrict__ x, const float* __restrict__ pooled,
                                const float* __restrict__ w_up, const float* __restrict__ b_up,
                                const float* __restrict__ g, const float* __restrict__ bta,
                                float* __restrict__ h) {
    int wave = threadIdx.x >> 6;
    int lane = threadIdx.x & 63;
    int row = blockIdx.x * 4 + wave;          // 5440 rows
    int b = row / S_TOT, s = row % S_TOT;
    float v0, v1;
    if (s < 2048) {
        const float* xr = x + (size_t)(b * 2048 + s) * 128;
        v0 = xr[lane]; v1 = xr[lane + 64];
    } else {
        int p = s - 2048;
        const float* pr = pooled + (size_t)(b * 672 + p) * 32;
        float a0 = b_up[lane], a1 = b_up[lane + 64];
        float a2 = 0.f, a3 = 0.f;
#pragma unroll
        for (int k = 0; k < 32; k += 2) {
            float p0 = pr[k], p1 = pr[k + 1];
            a0 += p0 * w_up[k * 128 + lane];
            a1 += p0 * w_up[k * 128 + lane + 64];
            a2 += p1 * w_up[(k + 1) * 128 + lane];
            a3 += p1 * w_up[(k + 1) * 128 + lane + 64];
        }
        v0 = a0 + a2; v1 = a1 + a3;
    }
    float sum = v0 + v1;
#pragma unroll
    for (int off = 32; off; off >>= 1) sum += __shfl_xor(sum, off);
    float mu = sum * (1.f / 128.f);
    float d0 = v0 - mu, d1 = v1 - mu;
    float vs = d0 * d0 + d1 * d1;
#pragma unroll
    for (int off = 32; off; off >>= 1) vs += __shfl_xor(vs, off);
    float inv = rsqrtf(vs * (1.f / 128.f) + 1e-5f);
    h[(size_t)row * 128 + lane]      = d0 * inv * g[lane]      + bta[lane];
    h[(size_t)row * 128 + lane + 64] = d1 * inv * g[lane + 64] + bta[lane + 64];
}

// ---------------- MFMA QKV: 340 blocks x 16 rows, 4 waves x 6 col-tiles (3 mats x 8 tiles).
__global__ __launch_bounds__(256) void qkv_mfma_kernel(const float* __restrict__ H,
                                                       const __hip_bfloat16* __restrict__ wqkvt,
                                                       float* __restrict__ q,
                                                       float* __restrict__ k,
                                                       float* __restrict__ v) {
    __shared__ __hip_bfloat16 hsb[16][136];
    int tid = threadIdx.x;
    int r0 = blockIdx.x * 16;                 // 340 blocks
    {
        int row = tid >> 4, c0 = (tid & 15) * 8;
        const float* src = &H[(size_t)(r0 + row) * 128 + c0];
        float4 x0 = *(const float4*)src;
        float4 x1 = *(const float4*)(src + 4);
        __hip_bfloat16* d = &hsb[row][c0];
        d[0] = __float2bfloat16(x0.x); d[1] = __float2bfloat16(x0.y);
        d[2] = __float2bfloat16(x0.z); d[3] = __float2bfloat16(x0.w);
        d[4] = __float2bfloat16(x1.x); d[5] = __float2bfloat16(x1.y);
        d[6] = __float2bfloat16(x1.z); d[7] = __float2bfloat16(x1.w);
    }
    __syncthreads();
    int lane = tid & 63, wv = tid >> 6;
    int l15 = lane & 15, grp = lane >> 4;
    bf16x8 afr[4];
#pragma unroll
    for (int ks = 0; ks < 4; ++ks)
        afr[ks] = *(const bf16x8*)&hsb[l15][ks * 32 + grp * 8];
    float* O[3] = {q, k, v};
#pragma unroll
    for (int t = 0; t < 6; ++t) {
        int gt = wv * 6 + t;                  // 0..23
        int mat = gt >> 3, jj = gt & 7;
        int j0 = jj * 16;
        f32x4 acc = {0.f, 0.f, 0.f, 0.f};
        const __hip_bfloat16* wb = &wqkvt[(size_t)(mat * 128 + j0 + l15) * 128 + grp * 8];
#pragma unroll
        for (int ks = 0; ks < 4; ++ks) {
            bf16x8 bfr = *(const bf16x8*)&wb[ks * 32];
            acc = __builtin_amdgcn_mfma_f32_16x16x32_bf16(afr[ks], bfr, acc, 0, 0, 0);
        }
        float* Om = O[mat];
#pragma unroll
        for (int i = 0; i < 4; ++i)
            Om[(size_t)(r0 + grp * 4 + i) * 128 + j0 + l15] = acc[i];
    }
}

// ---------------- sparse pyramid attention, 4 lanes per query (each owns 8 dims)
__global__ void attn_kernel(const float* __restrict__ Q, const float* __restrict__ K,
                            const float* __restrict__ V, float* __restrict__ O) {
    int id = blockIdx.x * 256 + threadIdx.x;     // 87040
    int d0 = (id & 3) * 8;
    int gid = id >> 2;                           // 21760 queries
    int i  = gid % S_TOT;
    int hh = (gid / S_TOT) & 3;
    int b  = gid / (S_TOT * 4);
    int li, s;
    if (i < 2048)      { li = 0; s = 0;    }
    else if (i < 2560) { li = 1; s = 2048; }
    else if (i < 2688) { li = 2; s = 2560; }
    else               { li = 3; s = 2688; }
    int sz = (li == 0) ? 2048 : (li == 1) ? 512 : (li == 2) ? 128 : 32;
    int pstart = (li == 0) ? 2048 : (li == 1) ? 2560 : 2688;
    int cstart = (li == 1) ? 0 : (li == 2) ? 2048 : 2560;

    const float* qp = Q + ((size_t)(b * S_TOT + i) * 128) + hh * 32 + d0;
    float4 qa = *(const float4*)qp;
    float4 qb = *(const float4*)(qp + 4);
    const float invt = 0.17677669529663687f;     // 1/sqrt(32)

    float sc[10];
    int   nj[10];
    bool  vl[10];
#pragma unroll
    for (int slot = 0; slot < 10; ++slot) {
        int j; bool valid;
        if (slot < 5)       { j = i - 2 + slot;                         valid = (j >= s) && (j < s + sz); }
        else if (slot == 5) { j = pstart + ((i - s) >> 2);              valid = (li < 3); }
        else                { j = cstart + ((i - s) << 2) + (slot - 6); valid = (li > 0); }
        nj[slot] = j; vl[slot] = valid;
        float dot = 0.f;
        if (valid) {
            const float* kp = K + ((size_t)(b * S_TOT + j) * 128) + hh * 32 + d0;
            float4 ka = *(const float4*)kp;
            float4 kb = *(const float4*)(kp + 4);
            dot = qa.x * ka.x + qa.y * ka.y + qa.z * ka.z + qa.w * ka.w
                + qb.x * kb.x + qb.y * kb.y + qb.z * kb.z + qb.w * kb.w;
        }
        dot += __shfl_xor(dot, 1);
        dot += __shfl_xor(dot, 2);
        sc[slot] = valid ? dot * invt : -1e30f;
    }
    float mx = sc[0];
#pragma unroll
    for (int slot = 1; slot < 10; ++slot) mx = fmaxf(mx, sc[slot]);
    float ssum = 0.f;
#pragma unroll
    for (int slot = 0; slot < 10; ++slot) { sc[slot] = __expf(sc[slot] - mx); ssum += sc[slot]; }
    float rinv = 1.f / ssum;
    float4 oa = {0.f, 0.f, 0.f, 0.f}, ob = {0.f, 0.f, 0.f, 0.f};
#pragma unroll
    for (int slot = 0; slot < 10; ++slot) {
        if (vl[slot]) {
            float p = sc[slot] * rinv;
            const float* vp = V + ((size_t)(b * S_TOT + nj[slot]) * 128) + hh * 32 + d0;
            float4 va = *(const float4*)vp;
            float4 vb = *(const float4*)(vp + 4);
            oa.x += p * va.x; oa.y += p * va.y; oa.z += p * va.z; oa.w += p * va.w;
            ob.x += p * vb.x; ob.y += p * vb.y; ob.z += p * vb.z; ob.w += p * vb.w;
        }
    }
    float* op = O + ((size_t)(b * S_TOT + i) * 128) + hh * 32 + d0;
    *(float4*)op = oa;
    *(float4*)(op + 4) = ob;
}

// ---------------- FUSED o-proj + LN1 + FFN + LN2 per 16-row tile. 340 blocks, 4 waves.
// o@wo -> +h_old -> LN1 -> h1 (fp32 LDS + bf16 LDS) -> GEMM1+ReLU -> GEMM2 -> +h1 -> LN2 -> h.
__global__ __launch_bounds__(256) void o_ffn_mfma_kernel(const float* __restrict__ Ob,
                                                         const __hip_bfloat16* __restrict__ wot,
                                                         const float* __restrict__ g1,
                                                         const float* __restrict__ b1ta,
                                                         const __hip_bfloat16* __restrict__ w1t,
                                                         const float* __restrict__ b1,
                                                         const __hip_bfloat16* __restrict__ w2t,
                                                         const float* __restrict__ b2,
                                                         const float* __restrict__ g2,
                                                         const float* __restrict__ b2ta,
                                                         float* __restrict__ h) {
    __shared__ __hip_bfloat16 osb[16][136];   // o tile bf16 (4.3 KB), reused as hsb after LN1
    __shared__ __hip_bfloat16 pb[16][520];    // relu(f1) bf16 (16.6 KB)
    __shared__ float partf[16][128];          // GEMM fp32 out (8 KB)
    __shared__ float h1s[16][128];            // LN1 output fp32 (8 KB) = FFN input/residual
    int tid = threadIdx.x;
    int r0 = blockIdx.x * 16;
    // stage o -> bf16 LDS
    {
        int row = tid >> 4, c0 = (tid & 15) * 8;
        const float* src = &Ob[(size_t)(r0 + row) * 128 + c0];
        float4 x0 = *(const float4*)src;
        float4 x1 = *(const float4*)(src + 4);
        __hip_bfloat16* d = &osb[row][c0];
        d[0] = __float2bfloat16(x0.x); d[1] = __float2bfloat16(x0.y);
        d[2] = __float2bfloat16(x0.z); d[3] = __float2bfloat16(x0.w);
        d[4] = __float2bfloat16(x1.x); d[5] = __float2bfloat16(x1.y);
        d[6] = __float2bfloat16(x1.z); d[7] = __float2bfloat16(x1.w);
    }
    __syncthreads();
    int lane = tid & 63, wv = tid >> 6;
    int l15 = lane & 15, grp = lane >> 4;
    // o-proj GEMM: 8 col-tiles over 4 waves (2 each)
    {
        bf16x8 afr[4];
#pragma unroll
        for (int ks = 0; ks < 4; ++ks)
            afr[ks] = *(const bf16x8*)&osb[l15][ks * 32 + grp * 8];
#pragma unroll
        for (int t = 0; t < 2; ++t) {
            int j0 = (wv * 2 + t) * 16;
            f32x4 acc = {0.f, 0.f, 0.f, 0.f};
            const __hip_bfloat16* wb = &wot[(size_t)(j0 + l15) * 128 + grp * 8];
#pragma unroll
            for (int ks = 0; ks < 4; ++ks) {
                bf16x8 bfr = *(const bf16x8*)&wb[ks * 32];
                acc = __builtin_amdgcn_mfma_f32_16x16x32_bf16(afr[ks], bfr, acc, 0, 0, 0);
            }
#pragma unroll
            for (int i = 0; i < 4; ++i)
                partf[grp * 4 + i][j0 + l15] = acc[i];
        }
    }
    __syncthreads();
    // LN1: h1 = LN(o@wo + h_old); write fp32 h1s + bf16 osb (reused as FFN A operand)
    {
        int r = tid >> 4, d0 = (tid & 15) * 8;
        size_t row = (size_t)(r0 + r) * 128;
        float vv[8];
        float sum = 0.f;
#pragma unroll
        for (int i = 0; i < 8; ++i) {
            int d = d0 + i;
            vv[i] = partf[r][d] + h[row + d];
            sum += vv[i];
        }
#pragma unroll
        for (int off = 8; off; off >>= 1) sum += __shfl_xor(sum, off);
        float mu = sum * (1.f / 128.f);
        float vs = 0.f;
#pragma unroll
        for (int i = 0; i < 8; ++i) { vv[i] -= mu; vs += vv[i] * vv[i]; }
#pragma unroll
        for (int off = 8; off; off >>= 1) vs += __shfl_xor(vs, off);
        float inv = rsqrtf(vs * (1.f / 128.f) + 1e-6f);
        __hip_bfloat16* db = &osb[r][d0];
#pragma unroll
        for (int i = 0; i < 8; ++i) {
            float hv = vv[i] * inv * g1[d0 + i] + b1ta[d0 + i];
            h1s[r][d0 + i] = hv;
            db[i] = __float2bfloat16(hv);
        }
    }
    __syncthreads();
    // FFN GEMM1: 32 col-tiles over 4 waves (8 each), bias+ReLU -> pb (bf16)
    {
        bf16x8 afr[4];
#pragma unroll
        for (int ks = 0; ks < 4; ++ks)
            afr[ks] = *(const bf16x8*)&osb[l15][ks * 32 + grp * 8];
#pragma unroll
        for (int t = 0; t < 8; ++t) {
            int j0 = (wv * 8 + t) * 16;
            f32x4 acc = {0.f, 0.f, 0.f, 0.f};
            const __hip_bfloat16* wb = &w1t[(size_t)(j0 + l15) * 128 + grp * 8];
#pragma unroll
            for (int ks = 0; ks < 4; ++ks) {
                bf16x8 bfr = *(const bf16x8*)&wb[ks * 32];
                acc = __builtin_amdgcn_mfma_f32_16x16x32_bf16(afr[ks], bfr, acc, 0, 0, 0);
            }
            float bv = b1[j0 + l15];
#pragma unroll
            for (int i = 0; i < 4; ++i)
                pb[grp * 4 + i][j0 + l15] = __float2bfloat16(fmaxf(acc[i] + bv, 0.f));
        }
    }
    __syncthreads();
    // FFN GEMM2: wave wv owns d-tiles wv*32, wv*32+16; K=512
    {
        f32x4 acc2a = {0.f, 0.f, 0.f, 0.f};
        f32x4 acc2b = {0.f, 0.f, 0.f, 0.f};
        const __hip_bfloat16* wb0 = &w2t[(size_t)(wv * 32 + l15) * 512 + grp * 8];
        const __hip_bfloat16* wb1 = &w2t[(size_t)(wv * 32 + 16 + l15) * 512 + grp * 8];
#pragma unroll
        for (int ks = 0; ks < 16; ++ks) {
            bf16x8 afr2 = *(const bf16x8*)&pb[l15][ks * 32 + grp * 8];
            bf16x8 b0 = *(const bf16x8*)&wb0[ks * 32];
            bf16x8 b1f = *(const bf16x8*)&wb1[ks * 32];
            acc2a = __builtin_amdgcn_mfma_f32_16x16x32_bf16(afr2, b0, acc2a, 0, 0, 0);
            acc2b = __builtin_amdgcn_mfma_f32_16x16x32_bf16(afr2, b1f, acc2b, 0, 0, 0);
        }
#pragma unroll
        for (int i = 0; i < 4; ++i) {
            partf[grp * 4 + i][wv * 32 + l15]      = acc2a[i];
            partf[grp * 4 + i][wv * 32 + 16 + l15] = acc2b[i];
        }
    }
    __syncthreads();
    // final: + b2 + h1 residual (from LDS) -> LN2 -> h global
    {
        int r = tid >> 4, d0 = (tid & 15) * 8;
        size_t row = (size_t)(r0 + r) * 128;
        float vv[8];
        float sum = 0.f;
#pragma unroll
        for (int i = 0; i < 8; ++i) {
            int d = d0 + i;
            vv[i] = partf[r][d] + b2[d] + h1s[r][d];
            sum += vv[i];
        }
#pragma unroll
        for (int off = 8; off; off >>= 1) sum += __shfl_xor(sum, off);
        float mu = sum * (1.f / 128.f);
        float vs = 0.f;
#pragma unroll
        for (int i = 0; i < 8; ++i) { vv[i] -= mu; vs += vv[i] * vv[i]; }
#pragma unroll
        for (int off = 8; off; off >>= 1) vs += __shfl_xor(vs, off);
        float inv = rsqrtf(vs * (1.f / 128.f) + 1e-6f);
#pragma unroll
        for (int i = 0; i < 8; ++i) vv[i] = vv[i] * inv * g2[d0 + i] + b2ta[d0 + i];
        *(float4*)&h[row + d0]     = make_float4(vv[0], vv[1], vv[2], vv[3]);
        *(float4*)&h[row + d0 + 4] = make_float4(vv[4], vv[5], vv[6], vv[7]);
    }
}

// ---------------- gather refer-points, float4
__global__ void gather_kernel(const float* __restrict__ H, const int* __restrict__ idx,
                              float* __restrict__ out) {
    int id = blockIdx.x * 256 + threadIdx.x;     // 524288 float4s
    int d4 = id & 31;
    int j = (id >> 5) & 3;
    int t = (id >> 7) & 2047;
    int b = id >> 18;
    int src = idx[t * 4 + j];
    ((float4*)out)[id] = *(const float4*)&H[((size_t)(b * S_TOT + src) * 128) + d4 * 4];
}

extern "C" void kernel_launch(void* const* d_in, const int* in_sizes, int n_in,
                              void* d_out, int out_size, void* d_ws, size_t ws_size,
                              hipStream_t stream) {
    (void)in_sizes; (void)n_in; (void)out_size; (void)ws_size;
    const float* x       = (const float*)d_in[0];
    const float* w_down  = (const float*)d_in[1];
    const float* b_down  = (const float*)d_in[2];
    const float* conv_w  = (const float*)d_in[3];
    const float* conv_b  = (const float*)d_in[4];
    const float* bn_g    = (const float*)d_in[5];
    const float* bn_b    = (const float*)d_in[6];
    const float* bn_m    = (const float*)d_in[7];
    const float* bn_v    = (const float*)d_in[8];
    const float* w_up    = (const float*)d_in[9];
    const float* b_up    = (const float*)d_in[10];
    const float* ln0_g   = (const float*)d_in[11];
    const float* ln0_b   = (const float*)d_in[12];
    const float* wq      = (const float*)d_in[13];
    const float* wk      = (const float*)d_in[14];
    const float* wv      = (const float*)d_in[15];
    const float* wo      = (const float*)d_in[16];
    const float* ln1_g   = (const float*)d_in[17];
    const float* ln1_b   = (const float*)d_in[18];
    const float* ffn_w1  = (const float*)d_in[19];
    const float* ffn_b1  = (const float*)d_in[20];
    const float* ffn_w2  = (const float*)d_in[21];
    const float* ffn_b2  = (const float*)d_in[22];
    const float* ln2_g   = (const float*)d_in[23];
    const float* ln2_b   = (const float*)d_in[24];
    const int* indexes   = (const int*)d_in[26];

    float* ws = (float*)d_ws;
    float* t0     = ws;               // 131072
    float* pooled = ws + 131072;      // 43008
    float* h      = ws + 174080;      // 696320
    float* q      = ws + 870400;      // 696320
    float* k      = ws + 1566720;     // 696320
    float* v      = ws + 2263040;     // 696320
    float* o      = ws + 2959360;     // 696320
    __hip_bfloat16* wb_all = (__hip_bfloat16*)(ws + 3655680);  // 393216 bf16
    __hip_bfloat16* w1t   = wb_all;            // [2][512][128]
    __hip_bfloat16* w2t   = wb_all + 131072;   // [2][128][512]
    __hip_bfloat16* wqkvt = wb_all + 262144;   // [2][3][128][128]
    __hip_bfloat16* wot   = wb_all + 360448;   // [2][128][128]

    cvt_all_kernel<<<1536, 256, 0, stream>>>(ffn_w1, ffn_w2, wq, wk, wv, wo, wb_all);

    down_kernel<<<512, 256, 0, stream>>>(x, w_down, b_down, t0);
    conv_kernel<<<128, 256, 0, stream>>>(t0, pooled, conv_w, conv_b, bn_g, bn_b, bn_m, bn_v,
                                         0, 2048, 0, 512, 0, 32768);
    conv_kernel<<<32, 256, 0, stream>>>(pooled, pooled, conv_w, conv_b, bn_g, bn_b, bn_m, bn_v,
                                        1, 672, 0, 128, 512, 8192);
    conv_kernel<<<8, 256, 0, stream>>>(pooled, pooled, conv_w, conv_b, bn_g, bn_b, bn_m, bn_v,
                                       2, 672, 512, 32, 640, 2048);
    build_ln_kernel<<<1360, 256, 0, stream>>>(x, pooled, w_up, b_up, ln0_g, ln0_b, h);

    for (int l = 0; l < 2; ++l) {
        qkv_mfma_kernel<<<340, 256, 0, stream>>>(h, wqkvt + l * 49152, q, k, v);
        attn_kernel<<<340, 256, 0, stream>>>(q, k, v, o);
        o_ffn_mfma_kernel<<<340, 256, 0, stream>>>(o, wot + l * 16384,
                                                   ln1_g + l * 128, ln1_b + l * 128,
                                                   w1t + l * 65536, ffn_b1 + l * 512,
                                                   w2t + l * 65536, ffn_b2 + l * 128,
                                                   ln2_g + l * 128, ln2_b + l * 128, h);
    }
    gather_kernel<<<2048, 256, 0, stream>>>(h, indexes, (float*)d_out);
}

// Round 19
// 114.939 us; speedup vs baseline: 1.7493x; 1.1060x over previous
//
#include <hip/hip_runtime.h>
#include <hip/hip_bf16.h>

#define S_TOT 2720

typedef short bf16x8 __attribute__((ext_vector_type(8)));
typedef float f32x4 __attribute__((ext_vector_type(4)));

// ---------------- all weight transpose+cvt in one kernel (393216 elems = 1536 blocks)
__global__ void cvt_all_kernel(const float* __restrict__ w1, const float* __restrict__ w2,
                               const float* __restrict__ wq, const float* __restrict__ wk,
                               const float* __restrict__ wv, const float* __restrict__ wo,
                               __hip_bfloat16* __restrict__ out) {
    int id = blockIdx.x * 256 + threadIdx.x;
    if (id < 131072) {                        // w1t[l][j][k] = w1[l][k][j]
        int l = id >> 16, r = id & 65535;
        int j = r >> 7, k = r & 127;
        out[id] = __float2bfloat16(w1[l * 65536 + k * 512 + j]);
    } else if (id < 262144) {                 // w2t[l][d][j] = w2[l][j][d]
        int t = id - 131072;
        int l = t >> 16, r = t & 65535;
        int d = r >> 9, j = r & 511;
        out[id] = __float2bfloat16(w2[l * 65536 + j * 128 + d]);
    } else if (id < 360448) {                 // wqkvt[l][m][j][k] = W_m[l][k][j]
        int t = id - 262144;
        int l = t / 49152, r = t % 49152;
        int m = r >> 14, rr = r & 16383;
        int j = rr >> 7, k = rr & 127;
        const float* W = (m == 0) ? wq : (m == 1) ? wk : wv;
        out[id] = __float2bfloat16(W[l * 16384 + k * 128 + j]);
    } else {                                  // wot[l][j][k] = wo[l][k][j]
        int t = id - 360448;
        int l = t >> 14, r = t & 16383;
        int j = r >> 7, k = r & 127;
        out[id] = __float2bfloat16(wo[l * 16384 + k * 128 + j]);
    }
}

// ---------------- down projection
__global__ void down_kernel(const float* __restrict__ x, const float* __restrict__ w,
                            const float* __restrict__ b, float* __restrict__ t0) {
    int id = blockIdx.x * 256 + threadIdx.x;     // 131072
    int c = id & 31;
    int r = id >> 5;
    const float* xr = x + (size_t)r * 128;
    float a0 = b[c], a1 = 0.f, a2 = 0.f, a3 = 0.f;
#pragma unroll
    for (int k = 0; k < 128; k += 4) {
        a0 += xr[k]     * w[(k)     * 32 + c];
        a1 += xr[k + 1] * w[(k + 1) * 32 + c];
        a2 += xr[k + 2] * w[(k + 2) * 32 + c];
        a3 += xr[k + 3] * w[(k + 3) * 32 + c];
    }
    t0[id] = (a0 + a1) + (a2 + a3);
}

// ---------------- conv (stride4,k4) + bias + BN + ELU
__global__ void conv_kernel(const float* __restrict__ in, float* __restrict__ pooled,
                            const float* __restrict__ cw, const float* __restrict__ cb,
                            const float* __restrict__ bg, const float* __restrict__ bb,
                            const float* __restrict__ bm, const float* __restrict__ bv,
                            int level, int in_bstride, int in_off, int Lout, int out_off,
                            int total) {
    int id = blockIdx.x * 256 + threadIdx.x;
    if (id >= total) return;
    int co = id & 31;
    int lo = (id >> 5) % Lout;
    int b  = id / (32 * Lout);
    const float* ib = in + (size_t)(b * in_bstride + in_off + lo * 4) * 32;
    const float* w  = cw + (size_t)(level * 32 + co) * 32 * 4;
    float acc0 = 0.f, acc1 = 0.f, acc2 = 0.f, acc3 = 0.f;
#pragma unroll
    for (int ci = 0; ci < 32; ++ci) {
        acc0 += ib[0 * 32 + ci] * w[ci * 4 + 0];
        acc1 += ib[1 * 32 + ci] * w[ci * 4 + 1];
        acc2 += ib[2 * 32 + ci] * w[ci * 4 + 2];
        acc3 += ib[3 * 32 + ci] * w[ci * 4 + 3];
    }
    float acc = ((acc0 + acc1) + (acc2 + acc3)) + cb[level * 32 + co];
    acc = (acc - bm[level * 32 + co]) * rsqrtf(bv[level * 32 + co] + 1e-5f)
          * bg[level * 32 + co] + bb[level * 32 + co];
    acc = acc > 0.f ? acc : expm1f(acc);
    pooled[(size_t)(b * 672 + out_off + lo) * 32 + co] = acc;
}

// ---------------- build h rows fused with LN0. wave per row.
__global__ void build_ln_kernel(const float* __restrict__ x, const float* __restrict__ pooled,
                                const float* __restrict__ w_up, const float* __restrict__ b_up,
                                const float* __restrict__ g, const float* __restrict__ bta,
                                float* __restrict__ h) {
    int wave = threadIdx.x >> 6;
    int lane = threadIdx.x & 63;
    int row = blockIdx.x * 4 + wave;          // 5440 rows
    int b = row / S_TOT, s = row % S_TOT;
    float v0, v1;
    if (s < 2048) {
        const float* xr = x + (size_t)(b * 2048 + s) * 128;
        v0 = xr[lane]; v1 = xr[lane + 64];
    } else {
        int p = s - 2048;
        const float* pr = pooled + (size_t)(b * 672 + p) * 32;
        float a0 = b_up[lane], a1 = b_up[lane + 64];
        float a2 = 0.f, a3 = 0.f;
#pragma unroll
        for (int k = 0; k < 32; k += 2) {
            float p0 = pr[k], p1 = pr[k + 1];
            a0 += p0 * w_up[k * 128 + lane];
            a1 += p0 * w_up[k * 128 + lane + 64];
            a2 += p1 * w_up[(k + 1) * 128 + lane];
            a3 += p1 * w_up[(k + 1) * 128 + lane + 64];
        }
        v0 = a0 + a2; v1 = a1 + a3;
    }
    float sum = v0 + v1;
#pragma unroll
    for (int off = 32; off; off >>= 1) sum += __shfl_xor(sum, off);
    float mu = sum * (1.f / 128.f);
    float d0 = v0 - mu, d1 = v1 - mu;
    float vs = d0 * d0 + d1 * d1;
#pragma unroll
    for (int off = 32; off; off >>= 1) vs += __shfl_xor(vs, off);
    float inv = rsqrtf(vs * (1.f / 128.f) + 1e-5f);
    h[(size_t)row * 128 + lane]      = d0 * inv * g[lane]      + bta[lane];
    h[(size_t)row * 128 + lane + 64] = d1 * inv * g[lane + 64] + bta[lane + 64];
}

// ---------------- MFMA QKV: 340 blocks x 16 rows, 4 waves x 6 col-tiles.
__global__ __launch_bounds__(256) void qkv_mfma_kernel(const float* __restrict__ H,
                                                       const __hip_bfloat16* __restrict__ wqkvt,
                                                       float* __restrict__ q,
                                                       float* __restrict__ k,
                                                       float* __restrict__ v) {
    __shared__ __hip_bfloat16 hsb[16][136];
    int tid = threadIdx.x;
    int r0 = blockIdx.x * 16;
    {
        int row = tid >> 4, c0 = (tid & 15) * 8;
        const float* src = &H[(size_t)(r0 + row) * 128 + c0];
        float4 x0 = *(const float4*)src;
        float4 x1 = *(const float4*)(src + 4);
        __hip_bfloat16* d = &hsb[row][c0];
        d[0] = __float2bfloat16(x0.x); d[1] = __float2bfloat16(x0.y);
        d[2] = __float2bfloat16(x0.z); d[3] = __float2bfloat16(x0.w);
        d[4] = __float2bfloat16(x1.x); d[5] = __float2bfloat16(x1.y);
        d[6] = __float2bfloat16(x1.z); d[7] = __float2bfloat16(x1.w);
    }
    __syncthreads();
    int lane = tid & 63, wv = tid >> 6;
    int l15 = lane & 15, grp = lane >> 4;
    bf16x8 afr[4];
#pragma unroll
    for (int ks = 0; ks < 4; ++ks)
        afr[ks] = *(const bf16x8*)&hsb[l15][ks * 32 + grp * 8];
    float* O[3] = {q, k, v};
#pragma unroll
    for (int t = 0; t < 6; ++t) {
        int gt = wv * 6 + t;
        int mat = gt >> 3, jj = gt & 7;
        int j0 = jj * 16;
        f32x4 acc = {0.f, 0.f, 0.f, 0.f};
        const __hip_bfloat16* wb = &wqkvt[(size_t)(mat * 128 + j0 + l15) * 128 + grp * 8];
#pragma unroll
        for (int ks = 0; ks < 4; ++ks) {
            bf16x8 bfr = *(const bf16x8*)&wb[ks * 32];
            acc = __builtin_amdgcn_mfma_f32_16x16x32_bf16(afr[ks], bfr, acc, 0, 0, 0);
        }
        float* Om = O[mat];
#pragma unroll
        for (int i = 0; i < 4; ++i)
            Om[(size_t)(r0 + grp * 4 + i) * 128 + j0 + l15] = acc[i];
    }
}

// ---------------- FUSED attn + o-proj + LN1 + FFN + LN2 per 16-row tile. 340 blocks.
// Phase A: sparse attention (thread = rl*16 + hh*4 + qd) -> osb bf16 LDS (no global o).
// Phase B: o@wo -> +h -> LN1 -> GEMM1+ReLU -> GEMM2 -> +h1 -> LN2 -> h.
__global__ __launch_bounds__(256) void attn_o_ffn_kernel(const float* __restrict__ Q,
                                                         const float* __restrict__ K,
                                                         const float* __restrict__ V,
                                                         const __hip_bfloat16* __restrict__ wot,
                                                         const float* __restrict__ g1,
                                                         const float* __restrict__ b1ta,
                                                         const __hip_bfloat16* __restrict__ w1t,
                                                         const float* __restrict__ b1,
                                                         const __hip_bfloat16* __restrict__ w2t,
                                                         const float* __restrict__ b2,
                                                         const float* __restrict__ g2,
                                                         const float* __restrict__ b2ta,
                                                         float* __restrict__ h) {
    __shared__ __hip_bfloat16 osb[16][136];   // attn output bf16, reused as LN1-out operand
    __shared__ __hip_bfloat16 pb[16][520];    // relu(f1) bf16
    __shared__ float partf[16][128];          // GEMM fp32 out
    __shared__ float h1s[16][128];            // LN1 output fp32 (FFN residual)
    int tid = threadIdx.x;
    int r0 = blockIdx.x * 16;
    // ---- Phase A: sparse pyramid attention for this tile's 16 rows
    {
        int rl = tid >> 4;                    // row in tile
        int hh = (tid >> 2) & 3;              // head
        int qd = tid & 3;                     // quarter (8 dims)
        int d0 = qd * 8;
        int row = r0 + rl;
        int b = row / S_TOT, i = row % S_TOT;
        int li, s;
        if (i < 2048)      { li = 0; s = 0;    }
        else if (i < 2560) { li = 1; s = 2048; }
        else if (i < 2688) { li = 2; s = 2560; }
        else               { li = 3; s = 2688; }
        int sz = (li == 0) ? 2048 : (li == 1) ? 512 : (li == 2) ? 128 : 32;
        int pstart = (li == 0) ? 2048 : (li == 1) ? 2560 : 2688;
        int cstart = (li == 1) ? 0 : (li == 2) ? 2048 : 2560;

        const float* qp = Q + ((size_t)row * 128) + hh * 32 + d0;
        float4 qa = *(const float4*)qp;
        float4 qb = *(const float4*)(qp + 4);
        const float invt = 0.17677669529663687f;   // 1/sqrt(32)

        float sc[10];
        int   nj[10];
        bool  vl[10];
#pragma unroll
        for (int slot = 0; slot < 10; ++slot) {
            int j; bool valid;
            if (slot < 5)       { j = i - 2 + slot;                         valid = (j >= s) && (j < s + sz); }
            else if (slot == 5) { j = pstart + ((i - s) >> 2);              valid = (li < 3); }
            else                { j = cstart + ((i - s) << 2) + (slot - 6); valid = (li > 0); }
            nj[slot] = j; vl[slot] = valid;
            float dot = 0.f;
            if (valid) {
                const float* kp = K + ((size_t)(b * S_TOT + j) * 128) + hh * 32 + d0;
                float4 ka = *(const float4*)kp;
                float4 kb = *(const float4*)(kp + 4);
                dot = qa.x * ka.x + qa.y * ka.y + qa.z * ka.z + qa.w * ka.w
                    + qb.x * kb.x + qb.y * kb.y + qb.z * kb.z + qb.w * kb.w;
            }
            dot += __shfl_xor(dot, 1);
            dot += __shfl_xor(dot, 2);
            sc[slot] = valid ? dot * invt : -1e30f;
        }
        float mx = sc[0];
#pragma unroll
        for (int slot = 1; slot < 10; ++slot) mx = fmaxf(mx, sc[slot]);
        float ssum = 0.f;
#pragma unroll
        for (int slot = 0; slot < 10; ++slot) { sc[slot] = __expf(sc[slot] - mx); ssum += sc[slot]; }
        float rinv = 1.f / ssum;
        float4 oa = {0.f, 0.f, 0.f, 0.f}, ob = {0.f, 0.f, 0.f, 0.f};
#pragma unroll
        for (int slot = 0; slot < 10; ++slot) {
            if (vl[slot]) {
                float p = sc[slot] * rinv;
                const float* vp = V + ((size_t)(b * S_TOT + nj[slot]) * 128) + hh * 32 + d0;
                float4 va = *(const float4*)vp;
                float4 vb = *(const float4*)(vp + 4);
                oa.x += p * va.x; oa.y += p * va.y; oa.z += p * va.z; oa.w += p * va.w;
                ob.x += p * vb.x; ob.y += p * vb.y; ob.z += p * vb.z; ob.w += p * vb.w;
            }
        }
        __hip_bfloat16* dst = &osb[rl][hh * 32 + d0];
        dst[0] = __float2bfloat16(oa.x); dst[1] = __float2bfloat16(oa.y);
        dst[2] = __float2bfloat16(oa.z); dst[3] = __float2bfloat16(oa.w);
        dst[4] = __float2bfloat16(ob.x); dst[5] = __float2bfloat16(ob.y);
        dst[6] = __float2bfloat16(ob.z); dst[7] = __float2bfloat16(ob.w);
    }
    __syncthreads();
    int lane = tid & 63, wv = tid >> 6;
    int l15 = lane & 15, grp = lane >> 4;
    // ---- o-proj GEMM: 8 col-tiles over 4 waves (2 each)
    {
        bf16x8 afr[4];
#pragma unroll
        for (int ks = 0; ks < 4; ++ks)
            afr[ks] = *(const bf16x8*)&osb[l15][ks * 32 + grp * 8];
#pragma unroll
        for (int t = 0; t < 2; ++t) {
            int j0 = (wv * 2 + t) * 16;
            f32x4 acc = {0.f, 0.f, 0.f, 0.f};
            const __hip_bfloat16* wb = &wot[(size_t)(j0 + l15) * 128 + grp * 8];
#pragma unroll
            for (int ks = 0; ks < 4; ++ks) {
                bf16x8 bfr = *(const bf16x8*)&wb[ks * 32];
                acc = __builtin_amdgcn_mfma_f32_16x16x32_bf16(afr[ks], bfr, acc, 0, 0, 0);
            }
#pragma unroll
            for (int i = 0; i < 4; ++i)
                partf[grp * 4 + i][j0 + l15] = acc[i];
        }
    }
    __syncthreads();
    // ---- LN1: h1 = LN(o@wo + h_old); fp32 -> h1s, bf16 -> osb (FFN A operand)
    {
        int r = tid >> 4, d0 = (tid & 15) * 8;
        size_t row = (size_t)(r0 + r) * 128;
        float vv[8];
        float sum = 0.f;
#pragma unroll
        for (int i = 0; i < 8; ++i) {
            int d = d0 + i;
            vv[i] = partf[r][d] + h[row + d];
            sum += vv[i];
        }
#pragma unroll
        for (int off = 8; off; off >>= 1) sum += __shfl_xor(sum, off);
        float mu = sum * (1.f / 128.f);
        float vs = 0.f;
#pragma unroll
        for (int i = 0; i < 8; ++i) { vv[i] -= mu; vs += vv[i] * vv[i]; }
#pragma unroll
        for (int off = 8; off; off >>= 1) vs += __shfl_xor(vs, off);
        float inv = rsqrtf(vs * (1.f / 128.f) + 1e-6f);
        __hip_bfloat16* db = &osb[r][d0];
#pragma unroll
        for (int i = 0; i < 8; ++i) {
            float hv = vv[i] * inv * g1[d0 + i] + b1ta[d0 + i];
            h1s[r][d0 + i] = hv;
            db[i] = __float2bfloat16(hv);
        }
    }
    __syncthreads();
    // ---- FFN GEMM1 + ReLU -> pb
    {
        bf16x8 afr[4];
#pragma unroll
        for (int ks = 0; ks < 4; ++ks)
            afr[ks] = *(const bf16x8*)&osb[l15][ks * 32 + grp * 8];
#pragma unroll
        for (int t = 0; t < 8; ++t) {
            int j0 = (wv * 8 + t) * 16;
            f32x4 acc = {0.f, 0.f, 0.f, 0.f};
            const __hip_bfloat16* wb = &w1t[(size_t)(j0 + l15) * 128 + grp * 8];
#pragma unroll
            for (int ks = 0; ks < 4; ++ks) {
                bf16x8 bfr = *(const bf16x8*)&wb[ks * 32];
                acc = __builtin_amdgcn_mfma_f32_16x16x32_bf16(afr[ks], bfr, acc, 0, 0, 0);
            }
            float bv = b1[j0 + l15];
#pragma unroll
            for (int i = 0; i < 4; ++i)
                pb[grp * 4 + i][j0 + l15] = __float2bfloat16(fmaxf(acc[i] + bv, 0.f));
        }
    }
    __syncthreads();
    // ---- FFN GEMM2
    {
        f32x4 acc2a = {0.f, 0.f, 0.f, 0.f};
        f32x4 acc2b = {0.f, 0.f, 0.f, 0.f};
        const __hip_bfloat16* wb0 = &w2t[(size_t)(wv * 32 + l15) * 512 + grp * 8];
        const __hip_bfloat16* wb1 = &w2t[(size_t)(wv * 32 + 16 + l15) * 512 + grp * 8];
#pragma unroll
        for (int ks = 0; ks < 16; ++ks) {
            bf16x8 afr2 = *(const bf16x8*)&pb[l15][ks * 32 + grp * 8];
            bf16x8 b0 = *(const bf16x8*)&wb0[ks * 32];
            bf16x8 b1f = *(const bf16x8*)&wb1[ks * 32];
            acc2a = __builtin_amdgcn_mfma_f32_16x16x32_bf16(afr2, b0, acc2a, 0, 0, 0);
            acc2b = __builtin_amdgcn_mfma_f32_16x16x32_bf16(afr2, b1f, acc2b, 0, 0, 0);
        }
#pragma unroll
        for (int i = 0; i < 4; ++i) {
            partf[grp * 4 + i][wv * 32 + l15]      = acc2a[i];
            partf[grp * 4 + i][wv * 32 + 16 + l15] = acc2b[i];
        }
    }
    __syncthreads();
    // ---- final: + b2 + h1 -> LN2 -> h
    {
        int r = tid >> 4, d0 = (tid & 15) * 8;
        size_t row = (size_t)(r0 + r) * 128;
        float vv[8];
        float sum = 0.f;
#pragma unroll
        for (int i = 0; i < 8; ++i) {
            int d = d0 + i;
            vv[i] = partf[r][d] + b2[d] + h1s[r][d];
            sum += vv[i];
        }
#pragma unroll
        for (int off = 8; off; off >>= 1) sum += __shfl_xor(sum, off);
        float mu = sum * (1.f / 128.f);
        float vs = 0.f;
#pragma unroll
        for (int i = 0; i < 8; ++i) { vv[i] -= mu; vs += vv[i] * vv[i]; }
#pragma unroll
        for (int off = 8; off; off >>= 1) vs += __shfl_xor(vs, off);
        float inv = rsqrtf(vs * (1.f / 128.f) + 1e-6f);
#pragma unroll
        for (int i = 0; i < 8; ++i) vv[i] = vv[i] * inv * g2[d0 + i] + b2ta[d0 + i];
        *(float4*)&h[row + d0]     = make_float4(vv[0], vv[1], vv[2], vv[3]);
        *(float4*)&h[row + d0 + 4] = make_float4(vv[4], vv[5], vv[6], vv[7]);
    }
}

// ---------------- gather refer-points, float4
__global__ void gather_kernel(const float* __restrict__ H, const int* __restrict__ idx,
                              float* __restrict__ out) {
    int id = blockIdx.x * 256 + threadIdx.x;     // 524288 float4s
    int d4 = id & 31;
    int j = (id >> 5) & 3;
    int t = (id >> 7) & 2047;
    int b = id >> 18;
    int src = idx[t * 4 + j];
    ((float4*)out)[id] = *(const float4*)&H[((size_t)(b * S_TOT + src) * 128) + d4 * 4];
}

extern "C" void kernel_launch(void* const* d_in, const int* in_sizes, int n_in,
                              void* d_out, int out_size, void* d_ws, size_t ws_size,
                              hipStream_t stream) {
    (void)in_sizes; (void)n_in; (void)out_size; (void)ws_size;
    const float* x       = (const float*)d_in[0];
    const float* w_down  = (const float*)d_in[1];
    const float* b_down  = (const float*)d_in[2];
    const float* conv_w  = (const float*)d_in[3];
    const float* conv_b  = (const float*)d_in[4];
    const float* bn_g    = (const float*)d_in[5];
    const float* bn_b    = (const float*)d_in[6];
    const float* bn_m    = (const float*)d_in[7];
    const float* bn_v    = (const float*)d_in[8];
    const float* w_up    = (const float*)d_in[9];
    const float* b_up    = (const float*)d_in[10];
    const float* ln0_g   = (const float*)d_in[11];
    const float* ln0_b   = (const float*)d_in[12];
    const float* wq      = (const float*)d_in[13];
    const float* wk      = (const float*)d_in[14];
    const float* wv      = (const float*)d_in[15];
    const float* wo      = (const float*)d_in[16];
    const float* ln1_g   = (const float*)d_in[17];
    const float* ln1_b   = (const float*)d_in[18];
    const float* ffn_w1  = (const float*)d_in[19];
    const float* ffn_b1  = (const float*)d_in[20];
    const float* ffn_w2  = (const float*)d_in[21];
    const float* ffn_b2  = (const float*)d_in[22];
    const float* ln2_g   = (const float*)d_in[23];
    const float* ln2_b   = (const float*)d_in[24];
    const int* indexes   = (const int*)d_in[26];

    float* ws = (float*)d_ws;
    float* t0     = ws;               // 131072
    float* pooled = ws + 131072;      // 43008
    float* h      = ws + 174080;      // 696320
    float* q      = ws + 870400;      // 696320
    float* k      = ws + 1566720;     // 696320
    float* v      = ws + 2263040;     // 696320
    __hip_bfloat16* wb_all = (__hip_bfloat16*)(ws + 2959360);  // 393216 bf16
    __hip_bfloat16* w1t   = wb_all;            // [2][512][128]
    __hip_bfloat16* w2t   = wb_all + 131072;   // [2][128][512]
    __hip_bfloat16* wqkvt = wb_all + 262144;   // [2][3][128][128]
    __hip_bfloat16* wot   = wb_all + 360448;   // [2][128][128]

    cvt_all_kernel<<<1536, 256, 0, stream>>>(ffn_w1, ffn_w2, wq, wk, wv, wo, wb_all);

    down_kernel<<<512, 256, 0, stream>>>(x, w_down, b_down, t0);
    conv_kernel<<<128, 256, 0, stream>>>(t0, pooled, conv_w, conv_b, bn_g, bn_b, bn_m, bn_v,
                                         0, 2048, 0, 512, 0, 32768);
    conv_kernel<<<32, 256, 0, stream>>>(pooled, pooled, conv_w, conv_b, bn_g, bn_b, bn_m, bn_v,
                                        1, 672, 0, 128, 512, 8192);
    conv_kernel<<<8, 256, 0, stream>>>(pooled, pooled, conv_w, conv_b, bn_g, bn_b, bn_m, bn_v,
                                       2, 672, 512, 32, 640, 2048);
    build_ln_kernel<<<1360, 256, 0, stream>>>(x, pooled, w_up, b_up, ln0_g, ln0_b, h);

    for (int l = 0; l < 2; ++l) {
        qkv_mfma_kernel<<<340, 256, 0, stream>>>(h, wqkvt + l * 49152, q, k, v);
        attn_o_ffn_kernel<<<340, 256, 0, stream>>>(q, k, v, wot + l * 16384,
                                                   ln1_g + l * 128, ln1_b + l * 128,
                                                   w1t + l * 65536, ffn_b1 + l * 512,
                                                   w2t + l * 65536, ffn_b2 + l * 128,
                                                   ln2_g + l * 128, ln2_b + l * 128, h);
    }
    gather_kernel<<<2048, 256, 0, stream>>>(h, indexes, (float*)d_out);
}